// Round 1
// baseline (4755.600 us; speedup 1.0000x reference)
//
#include <hip/hip_runtime.h>
#include <math.h>

#define DMODEL 1024
#define NROWS  16384   // B*T
#define SEQLEN 4096

static __device__ __forceinline__ float sigmoidf_(float v) { return 1.f / (1.f + __expf(-v)); }

// ---------------- LayerNorm row stats ----------------
__global__ __launch_bounds__(256) void ln_stats_kernel(const float* __restrict__ x,
                                                       float* __restrict__ mean,
                                                       float* __restrict__ rstd) {
  int row = blockIdx.x;
  const float4* xr = (const float4*)(x + (size_t)row * DMODEL);
  float4 v = xr[threadIdx.x];
  float s  = v.x + v.y + v.z + v.w;
  float s2 = v.x*v.x + v.y*v.y + v.z*v.z + v.w*v.w;
  #pragma unroll
  for (int off = 32; off > 0; off >>= 1) {
    s  += __shfl_down(s, off);
    s2 += __shfl_down(s2, off);
  }
  __shared__ float sh[4], sh2[4];
  int lane = threadIdx.x & 63, wid = threadIdx.x >> 6;
  if (lane == 0) { sh[wid] = s; sh2[wid] = s2; }
  __syncthreads();
  if (threadIdx.x == 0) {
    s = sh[0] + sh[1] + sh[2] + sh[3];
    s2 = sh2[0] + sh2[1] + sh2[2] + sh2[3];
    float m = s * (1.f / DMODEL);
    float var = fmaxf(s2 * (1.f / DMODEL) - m * m, 0.f);
    mean[row] = m;
    rstd[row] = rsqrtf(var + 1e-5f);
  }
}

#define RANK1_UPDATE(ACC, AV, BV)                                                   \
  ACC[0][0] += AV.x * BV.x; ACC[0][1] += AV.x * BV.y; ACC[0][2] += AV.x * BV.z; ACC[0][3] += AV.x * BV.w; \
  ACC[1][0] += AV.y * BV.x; ACC[1][1] += AV.y * BV.y; ACC[1][2] += AV.y * BV.z; ACC[1][3] += AV.y * BV.w; \
  ACC[2][0] += AV.z * BV.x; ACC[2][1] += AV.z * BV.y; ACC[2][2] += AV.z * BV.z; ACC[2][3] += AV.z * BV.w; \
  ACC[3][0] += AV.w * BV.x; ACC[3][1] += AV.w * BV.y; ACC[3][2] += AV.w * BV.z; ACC[3][3] += AV.w * BV.w;

// ---------------- Generic 64x64-tile fp32 GEMM (K = 1024), out[r][n] = sum_k A[r][k]*B[n][k] ----------------
// LNMODE: 0 plain A, 1 apply LN(mean,rstd,lng,lnb) to A on load.
// EPI: 0 silu(acc + bias[bias_off+col]) -> out
//      1 out = res + b2v[col] + acc
//      2 out += acc
//      3 out = acc
template<int LNMODE, int EPI>
__global__ __launch_bounds__(256) void gemm_kernel(
    const float* __restrict__ A,
    const float* __restrict__ B1, const float* __restrict__ B2, int nsplit, int ldb,
    const float* __restrict__ mean, const float* __restrict__ rstd,
    const float* __restrict__ lng, const float* __restrict__ lnb,
    const float* __restrict__ bias, int bias_off,
    const float* __restrict__ res, const float* __restrict__ b2v,
    float* __restrict__ out, int ldout) {
  __shared__ float As[32][68];
  __shared__ float Bs[32][68];
  const int tid = threadIdx.x;
  const int tx = tid & 15, ty = tid >> 4;
  const int n0 = blockIdx.x * 64, r0 = blockIdx.y * 64;
  float acc[4][4] = {};
  for (int k0 = 0; k0 < 1024; k0 += 32) {
    __syncthreads();
    #pragma unroll
    for (int p = 0; p < 8; ++p) {
      int idx = tid + p * 256;
      int row = idx >> 5, kk = idx & 31;
      int gr = r0 + row, gk = k0 + kk;
      float v = A[(size_t)gr * 1024 + gk];
      if (LNMODE) v = (v - mean[gr]) * rstd[gr] * lng[gk] + lnb[gk];
      As[kk][row] = v;
    }
    #pragma unroll
    for (int p = 0; p < 8; ++p) {
      int idx = tid + p * 256;
      int n = idx >> 5, kk = idx & 31;
      int ng = n0 + n;
      const float* bp = (ng < nsplit) ? B1 : B2;
      int nr = (ng < nsplit) ? ng : ng - nsplit;
      Bs[kk][n] = bp[(size_t)nr * ldb + k0 + kk];
    }
    __syncthreads();
    #pragma unroll
    for (int kk = 0; kk < 32; ++kk) {
      float4 av = *(const float4*)&As[kk][ty * 4];
      float4 bv = *(const float4*)&Bs[kk][tx * 4];
      RANK1_UPDATE(acc, av, bv)
    }
  }
  #pragma unroll
  for (int i = 0; i < 4; ++i) {
    int row = r0 + ty * 4 + i;
    int col = n0 + tx * 4;
    float4 o;
    if (EPI == 3) {
      o = make_float4(acc[i][0], acc[i][1], acc[i][2], acc[i][3]);
    } else if (EPI == 0) {
      float v0 = acc[i][0] + bias[bias_off + col + 0];
      float v1 = acc[i][1] + bias[bias_off + col + 1];
      float v2 = acc[i][2] + bias[bias_off + col + 2];
      float v3 = acc[i][3] + bias[bias_off + col + 3];
      o.x = v0 * sigmoidf_(v0); o.y = v1 * sigmoidf_(v1);
      o.z = v2 * sigmoidf_(v2); o.w = v3 * sigmoidf_(v3);
    } else if (EPI == 1) {
      float4 rv = *(const float4*)&res[(size_t)row * 1024 + col];
      o.x = rv.x + b2v[col + 0] + acc[i][0];
      o.y = rv.y + b2v[col + 1] + acc[i][1];
      o.z = rv.z + b2v[col + 2] + acc[i][2];
      o.w = rv.w + b2v[col + 3] + acc[i][3];
    } else {
      float4 rv = *(const float4*)&out[(size_t)row * ldout + col];
      o.x = rv.x + acc[i][0]; o.y = rv.y + acc[i][1];
      o.z = rv.z + acc[i][2]; o.w = rv.w + acc[i][3];
    }
    *(float4*)&out[(size_t)row * ldout + col] = o;
  }
}

// ---------------- elementwise: bd[16384,256] -> a,b arrays in [B,K,T] layout ----------------
__global__ __launch_bounds__(256) void ew_ab_kernel(
    const float* __restrict__ bd, const float* __restrict__ b_sel,
    const float* __restrict__ log_decay, const float* __restrict__ frequency,
    float* __restrict__ a_r, float* __restrict__ a_i,
    float* __restrict__ b_r, float* __restrict__ b_i) {
  __shared__ float T[32][257];
  int bb = blockIdx.x >> 7;            // 0..3
  int t0 = (blockIdx.x & 127) << 5;    // chunk of 32 timesteps
  int tid = threadIdx.x;
  #pragma unroll
  for (int p = 0; p < 32; ++p) {
    int idx = tid + p * 256;           // 32*256 elements
    int tt = idx >> 8, j = idx & 255;
    T[tt][j] = bd[((size_t)bb * 4096 + t0 + tt) * 256 + j];
  }
  __syncthreads();
  #pragma unroll
  for (int p = 0; p < 8; ++p) {
    int idx = tid + p * 256;           // 32 t x 64 k
    int tt = idx & 31, k = idx >> 5;
    float br_ = T[tt][k];
    float bi_ = T[tt][64 + k];
    float dd = T[tt][128 + k] + b_sel[k];
    float df = T[tt][192 + k] + b_sel[64 + k];
    float mag = sigmoidf_(log_decay[k] + 0.1f * tanhf(dd));
    float fr = frequency[k] + 0.05f * tanhf(df);
    float ar_ = mag * cosf(fr), ai_ = mag * sinf(fr);
    size_t o = ((size_t)bb * 64 + k) * 4096 + t0 + tt;
    a_r[o] = ar_; a_i[o] = ai_; b_r[o] = br_; b_i[o] = bi_;
  }
}

// ---------------- associative scan over T per (b,k) sequence ----------------
__global__ __launch_bounds__(256) void scan_kernel(
    const float* __restrict__ a_r, const float* __restrict__ a_i,
    const float* __restrict__ b_r, const float* __restrict__ b_i,
    float* __restrict__ c_r, float* __restrict__ c_i) {
  int seq = blockIdx.x;                // b*64 + k
  size_t base = (size_t)seq * SEQLEN;
  int tid = threadIdx.x;
  int t0 = tid * 16;
  float Ar = 1.f, Ai = 0.f, Br = 0.f, Bi = 0.f;
  #pragma unroll
  for (int s = 0; s < 16; ++s) {
    size_t t = base + t0 + s;
    float ar = a_r[t], ai = a_i[t], br = b_r[t], bi = b_i[t];
    float nBr = ar * Br - ai * Bi + br;
    float nBi = ar * Bi + ai * Br + bi;
    Br = nBr; Bi = nBi;
    float nAr = ar * Ar - ai * Ai;
    float nAi = ar * Ai + ai * Ar;
    Ar = nAr; Ai = nAi;
  }
  __shared__ float sAr[256], sAi[256], sBr[256], sBi[256];
  sAr[tid] = Ar; sAi[tid] = Ai; sBr[tid] = Br; sBi[tid] = Bi;
  for (int off = 1; off < 256; off <<= 1) {
    __syncthreads();
    float pAr = 0.f, pAi = 0.f, pBr = 0.f, pBi = 0.f;
    if (tid >= off) { pAr = sAr[tid - off]; pAi = sAi[tid - off]; pBr = sBr[tid - off]; pBi = sBi[tid - off]; }
    __syncthreads();
    if (tid >= off) {
      float cAr = sAr[tid], cAi = sAi[tid], cBr = sBr[tid], cBi = sBi[tid];
      float nBr = cAr * pBr - cAi * pBi + cBr;   // B = A_cur*B_prev + B_cur
      float nBi = cAr * pBi + cAi * pBr + cBi;
      float nAr = cAr * pAr - cAi * pAi;
      float nAi = cAr * pAi + cAi * pAr;
      sAr[tid] = nAr; sAi[tid] = nAi; sBr[tid] = nBr; sBi[tid] = nBi;
    }
  }
  __syncthreads();
  float cr = (tid > 0) ? sBr[tid - 1] : 0.f;
  float ci = (tid > 0) ? sBi[tid - 1] : 0.f;
  #pragma unroll
  for (int s = 0; s < 16; ++s) {
    size_t t = base + t0 + s;
    float ar = a_r[t], ai = a_i[t], br = b_r[t], bi = b_i[t];
    float nr = ar * cr - ai * ci + br;
    float ni = ar * ci + ai * cr + bi;
    cr = nr; ci = ni;
    c_r[t] = cr; c_i[t] = ci;
  }
}

// ---------------- fold R into W_out: Weff[d][col] ----------------
__global__ __launch_bounds__(256) void weff_kernel(const float* __restrict__ W_out,
                                                   const float* __restrict__ R,
                                                   float* __restrict__ Weff) {
  int idx = blockIdx.x * 256 + threadIdx.x;   // < 1024*128
  int d = idx >> 7, col = idx & 127;
  int k = col & 63, h = k >> 4, kk = k & 15;
  int off = (col < 64) ? 0 : 64;
  float s = 0.f;
  #pragma unroll
  for (int j = 0; j < 16; ++j)
    s += W_out[d * 128 + off + h * 16 + j] * R[h * 256 + j * 16 + kk];
  Weff[idx] = s;
}

// ---------------- fused gate GEMM (K=1024) + h GEMM (K=128) + residual ----------------
__global__ __launch_bounds__(256) void gate_kernel(
    const float* __restrict__ x, const float* __restrict__ W_g, const float* __restrict__ b_g,
    const float* __restrict__ mean1, const float* __restrict__ rstd1,
    const float* __restrict__ g1, const float* __restrict__ be1,
    const float* __restrict__ c_r, const float* __restrict__ c_i,
    const float* __restrict__ Weff,
    float* __restrict__ xmid) {
  __shared__ float As[32][68];
  __shared__ float Bs[32][68];
  const int tid = threadIdx.x;
  const int tx = tid & 15, ty = tid >> 4;
  const int n0 = blockIdx.x * 64, r0 = blockIdx.y * 64;
  float accg[4][4] = {};
  for (int k0 = 0; k0 < 1024; k0 += 32) {
    __syncthreads();
    #pragma unroll
    for (int p = 0; p < 8; ++p) {
      int idx = tid + p * 256;
      int row = idx >> 5, kk = idx & 31;
      int gr = r0 + row, gk = k0 + kk;
      float v = x[(size_t)gr * 1024 + gk];
      v = (v - mean1[gr]) * rstd1[gr] * g1[gk] + be1[gk];
      As[kk][row] = v;
    }
    #pragma unroll
    for (int p = 0; p < 8; ++p) {
      int idx = tid + p * 256;
      int n = idx >> 5, kk = idx & 31;
      Bs[kk][n] = W_g[(size_t)(n0 + n) * 1024 + k0 + kk];
    }
    __syncthreads();
    #pragma unroll
    for (int kk = 0; kk < 32; ++kk) {
      float4 av = *(const float4*)&As[kk][ty * 4];
      float4 bv = *(const float4*)&Bs[kk][tx * 4];
      RANK1_UPDATE(accg, av, bv)
    }
  }
  float acch[4][4] = {};
  const int bb = r0 >> 12;
  const int t0 = r0 & 4095;
  for (int j0 = 0; j0 < 128; j0 += 32) {
    __syncthreads();
    #pragma unroll
    for (int p = 0; p < 8; ++p) {
      int idx = tid + p * 256;
      int row = idx & 63, jj = idx >> 6;
      int j = j0 + jj;
      const float* cp = (j < 64) ? c_r : c_i;
      int jk = j & 63;
      As[jj][row] = cp[((size_t)bb * 64 + jk) * 4096 + t0 + row];
    }
    #pragma unroll
    for (int p = 0; p < 8; ++p) {
      int idx = tid + p * 256;
      int n = idx >> 5, kk = idx & 31;
      Bs[kk][n] = Weff[(size_t)(n0 + n) * 128 + j0 + kk];
    }
    __syncthreads();
    #pragma unroll
    for (int kk = 0; kk < 32; ++kk) {
      float4 av = *(const float4*)&As[kk][ty * 4];
      float4 bv = *(const float4*)&Bs[kk][tx * 4];
      RANK1_UPDATE(acch, av, bv)
    }
  }
  #pragma unroll
  for (int i = 0; i < 4; ++i) {
    int row = r0 + ty * 4 + i;
    int col = n0 + tx * 4;
    float4 xv = *(const float4*)&x[(size_t)row * 1024 + col];
    float4 o;
    o.x = xv.x + sigmoidf_(accg[i][0] + b_g[col + 0]) * acch[i][0];
    o.y = xv.y + sigmoidf_(accg[i][1] + b_g[col + 1]) * acch[i][1];
    o.z = xv.z + sigmoidf_(accg[i][2] + b_g[col + 2]) * acch[i][2];
    o.w = xv.w + sigmoidf_(accg[i][3] + b_g[col + 3]) * acch[i][3];
    *(float4*)&xmid[(size_t)row * 1024 + col] = o;
  }
}

extern "C" void kernel_launch(void* const* d_in, const int* in_sizes, int n_in,
                              void* d_out, int out_size, void* d_ws, size_t ws_size,
                              hipStream_t stream) {
  (void)in_sizes; (void)n_in; (void)out_size; (void)ws_size;
  const float* x         = (const float*)d_in[0];
  const float* W_in      = (const float*)d_in[1];
  const float* log_decay = (const float*)d_in[2];
  const float* frequency = (const float*)d_in[3];
  const float* W_sel     = (const float*)d_in[4];
  const float* b_sel     = (const float*)d_in[5];
  const float* R         = (const float*)d_in[6];
  const float* W_out     = (const float*)d_in[7];
  const float* W_g       = (const float*)d_in[8];
  const float* b_g       = (const float*)d_in[9];
  const float* g1        = (const float*)d_in[10];
  const float* be1       = (const float*)d_in[11];
  const float* g2        = (const float*)d_in[12];
  const float* be2       = (const float*)d_in[13];
  const float* W1        = (const float*)d_in[14];
  const float* b1        = (const float*)d_in[15];
  const float* W2        = (const float*)d_in[16];
  const float* b2        = (const float*)d_in[17];
  float* out = (float*)d_out;
  float* ws  = (float*)d_ws;

  float* mean1 = ws;
  float* rstd1 = ws + 16384;
  float* mean2 = ws + 32768;
  float* rstd2 = ws + 49152;
  float* a_r  = ws + 65536;
  float* a_i  = a_r + (1 << 20);
  float* b_rr = a_i + (1 << 20);
  float* b_ii = b_rr + (1 << 20);
  float* c_r  = b_ii + (1 << 20);
  float* c_i  = c_r + (1 << 20);
  float* bd   = c_i + (1 << 20);            // 16384 x 256
  float* Weff = bd + (size_t)16384 * 256;   // 1024 x 128
  float* xmid = Weff + 131072;              // 16384 x 1024
  float* mid  = xmid + (1 << 24);           // 16384 x 1024 (chunk)

  dim3 blk(256);
  const int NEVER = 1 << 30;

  // LN1 stats
  ln_stats_kernel<<<NROWS, blk, 0, stream>>>(x, mean1, rstd1);
  // beta/delta GEMM: [16384,1024] x [1024,256] -> bd (cols 0..127 = W_in, 128..255 = W_sel)
  gemm_kernel<1, 3><<<dim3(4, 256), blk, 0, stream>>>(
      x, W_in, W_sel, 128, 1024, mean1, rstd1, g1, be1,
      nullptr, 0, nullptr, nullptr, bd, 256);
  // elementwise a,b in [B,K,T]
  ew_ab_kernel<<<512, blk, 0, stream>>>(bd, b_sel, log_decay, frequency, a_r, a_i, b_rr, b_ii);
  // scan
  scan_kernel<<<256, blk, 0, stream>>>(a_r, a_i, b_rr, b_ii, c_r, c_i);
  // fold R into W_out
  weff_kernel<<<512, blk, 0, stream>>>(W_out, R, Weff);
  // gate + h + residual -> xmid
  gate_kernel<<<dim3(16, 256), blk, 0, stream>>>(x, W_g, b_g, mean1, rstd1, g1, be1,
                                                 c_r, c_i, Weff, xmid);
  // LN2 stats
  ln_stats_kernel<<<NROWS, blk, 0, stream>>>(xmid, mean2, rstd2);
  // MLP chunked over hidden dim (4 x 1024)
  for (int c = 0; c < 4; ++c) {
    gemm_kernel<1, 0><<<dim3(16, 256), blk, 0, stream>>>(
        xmid, W1 + (size_t)c * 1024 * 1024, W1, NEVER, 1024,
        mean2, rstd2, g2, be2, b1, c * 1024, nullptr, nullptr, mid, 1024);
    if (c == 0) {
      gemm_kernel<0, 1><<<dim3(16, 256), blk, 0, stream>>>(
          mid, W2 + (size_t)c * 1024, W2, NEVER, 4096,
          nullptr, nullptr, nullptr, nullptr, nullptr, 0, xmid, b2, out, 1024);
    } else {
      gemm_kernel<0, 2><<<dim3(16, 256), blk, 0, stream>>>(
          mid, W2 + (size_t)c * 1024, W2, NEVER, 4096,
          nullptr, nullptr, nullptr, nullptr, nullptr, 0, nullptr, nullptr, out, 1024);
    }
  }
}

// Round 2
// 827.812 us; speedup vs baseline: 5.7448x; 5.7448x over previous
//
#include <hip/hip_runtime.h>
#include <math.h>

typedef __bf16 bf16_t;
typedef __attribute__((ext_vector_type(8))) __bf16 bf16x8;
typedef __attribute__((ext_vector_type(4))) float f32x4;

#define DMODEL 1024
#define NROWS  16384   // B*T
#define SEQLEN 4096

static __device__ __forceinline__ float sigmoidf_(float v) { return 1.f / (1.f + __expf(-v)); }

#define GLOAD16(gsrc, ldst) __builtin_amdgcn_global_load_lds(                     \
    (const __attribute__((address_space(1))) void*)(gsrc),                        \
    (__attribute__((address_space(3))) void*)(ldst), 16, 0, 0)

// ---------------- LayerNorm row stats ----------------
__global__ __launch_bounds__(256) void ln_stats_kernel(const float* __restrict__ x,
                                                       float* __restrict__ mean,
                                                       float* __restrict__ rstd) {
  int row = blockIdx.x;
  const float4* xr = (const float4*)(x + (size_t)row * DMODEL);
  float4 v = xr[threadIdx.x];
  float s  = v.x + v.y + v.z + v.w;
  float s2 = v.x*v.x + v.y*v.y + v.z*v.z + v.w*v.w;
  #pragma unroll
  for (int off = 32; off > 0; off >>= 1) {
    s  += __shfl_down(s, off);
    s2 += __shfl_down(s2, off);
  }
  __shared__ float sh[4], sh2[4];
  int lane = threadIdx.x & 63, wid = threadIdx.x >> 6;
  if (lane == 0) { sh[wid] = s; sh2[wid] = s2; }
  __syncthreads();
  if (threadIdx.x == 0) {
    s = sh[0] + sh[1] + sh[2] + sh[3];
    s2 = sh2[0] + sh2[1] + sh2[2] + sh2[3];
    float m = s * (1.f / DMODEL);
    float var = fmaxf(s2 * (1.f / DMODEL) - m * m, 0.f);
    mean[row] = m;
    rstd[row] = rsqrtf(var + 1e-5f);
  }
}

// ---------------- LN apply + f32 -> bf16 ----------------
__global__ __launch_bounds__(256) void ln_to_bf16_kernel(const float* __restrict__ x,
                                                         const float* __restrict__ mean,
                                                         const float* __restrict__ rstd,
                                                         const float* __restrict__ g,
                                                         const float* __restrict__ b,
                                                         bf16_t* __restrict__ out) {
  size_t idx = ((size_t)blockIdx.x * 256 + threadIdx.x) * 8;
  int row = (int)(idx >> 10);
  int col = (int)(idx & 1023);
  float m = mean[row], rs = rstd[row];
  float4 v0 = *(const float4*)&x[idx];
  float4 v1 = *(const float4*)&x[idx + 4];
  float4 g0 = *(const float4*)&g[col];
  float4 g1v = *(const float4*)&g[col + 4];
  float4 b0 = *(const float4*)&b[col];
  float4 b1v = *(const float4*)&b[col + 4];
  union { bf16_t h[8]; float4 f4; } u;
  u.h[0] = (bf16_t)((v0.x - m) * rs * g0.x + b0.x);
  u.h[1] = (bf16_t)((v0.y - m) * rs * g0.y + b0.y);
  u.h[2] = (bf16_t)((v0.z - m) * rs * g0.z + b0.z);
  u.h[3] = (bf16_t)((v0.w - m) * rs * g0.w + b0.w);
  u.h[4] = (bf16_t)((v1.x - m) * rs * g1v.x + b1v.x);
  u.h[5] = (bf16_t)((v1.y - m) * rs * g1v.y + b1v.y);
  u.h[6] = (bf16_t)((v1.z - m) * rs * g1v.z + b1v.z);
  u.h[7] = (bf16_t)((v1.w - m) * rs * g1v.w + b1v.w);
  *(float4*)&out[idx] = u.f4;
}

// ---------------- plain f32 -> bf16 convert ----------------
__global__ __launch_bounds__(256) void f32_to_bf16_kernel(const float* __restrict__ in,
                                                          bf16_t* __restrict__ out, int n) {
  int idx = (blockIdx.x * 256 + threadIdx.x) * 4;
  if (idx >= n) return;
  float4 v = *(const float4*)&in[idx];
  out[idx + 0] = (bf16_t)v.x;
  out[idx + 1] = (bf16_t)v.y;
  out[idx + 2] = (bf16_t)v.z;
  out[idx + 3] = (bf16_t)v.w;
}

// ---------------- bf16 MFMA GEMM: C[M,N] = A[M,K] * B[N,K]^T ----------------
// 128x128 tile, BK=32, 4 waves (2x2), 4x4 frags of 16x16x32 per wave (m97 structure).
// EPI: 0 outf = acc (f32)
//      1 outb = bf16(silu(acc + bias[col]))
//      2 outf = res[row*1024+col] + b2v[col] + acc
//      3 outf += acc
template<int EPI>
__global__ __launch_bounds__(256) void gemm_bf16_kernel(
    const bf16_t* __restrict__ A, int lda,
    const bf16_t* __restrict__ B, int ldb, int K,
    const float* __restrict__ bias,
    const float* __restrict__ res, const float* __restrict__ b2v,
    float* __restrict__ outf, bf16_t* __restrict__ outb, int ldout) {
  __shared__ __align__(16) bf16_t As[128 * 32];
  __shared__ __align__(16) bf16_t Bs[128 * 32];
  const int tid = threadIdx.x;
  const int lane = tid & 63;
  const int w = tid >> 6;
  const int wr = w >> 1, wc = w & 1;
  const int n0 = blockIdx.x * 128, r0 = blockIdx.y * 128;

  const int srow0 = tid >> 2;             // staging row for p=0
  const int srow1 = 64 + (tid >> 2);      // p=1
  const int skk = (tid & 3) * 8;

  const int fr = lane & 15;
  const int ko = (lane >> 4) * 8;

  f32x4 acc[4][4];
  #pragma unroll
  for (int m = 0; m < 4; ++m)
    #pragma unroll
    for (int n = 0; n < 4; ++n) acc[m][n] = (f32x4){0.f, 0.f, 0.f, 0.f};

  for (int k0 = 0; k0 < K; k0 += 32) {
    GLOAD16(A + (size_t)(r0 + srow0) * lda + k0 + skk, (char*)As + w * 1024);
    GLOAD16(A + (size_t)(r0 + srow1) * lda + k0 + skk, (char*)As + 4096 + w * 1024);
    GLOAD16(B + (size_t)(n0 + srow0) * ldb + k0 + skk, (char*)Bs + w * 1024);
    GLOAD16(B + (size_t)(n0 + srow1) * ldb + k0 + skk, (char*)Bs + 4096 + w * 1024);
    __syncthreads();
    bf16x8 af[4], bfr[4];
    #pragma unroll
    for (int m = 0; m < 4; ++m)
      af[m] = *(const bf16x8*)&As[(wr * 64 + m * 16 + fr) * 32 + ko];
    #pragma unroll
    for (int n = 0; n < 4; ++n)
      bfr[n] = *(const bf16x8*)&Bs[(wc * 64 + n * 16 + fr) * 32 + ko];
    #pragma unroll
    for (int m = 0; m < 4; ++m)
      #pragma unroll
      for (int n = 0; n < 4; ++n)
        acc[m][n] = __builtin_amdgcn_mfma_f32_16x16x32_bf16(af[m], bfr[n], acc[m][n], 0, 0, 0);
    __syncthreads();
  }

  const int rbase = (lane >> 4) * 4;
  #pragma unroll
  for (int m = 0; m < 4; ++m) {
    #pragma unroll
    for (int n = 0; n < 4; ++n) {
      int row = r0 + wr * 64 + m * 16 + rbase;
      int col = n0 + wc * 64 + n * 16 + fr;
      f32x4 v = acc[m][n];
      #pragma unroll
      for (int j = 0; j < 4; ++j) {
        int r = row + j;
        float val = v[j];
        if (EPI == 0) {
          outf[(size_t)r * ldout + col] = val;
        } else if (EPI == 1) {
          float t = val + bias[col];
          t = t * sigmoidf_(t);
          outb[(size_t)r * ldout + col] = (bf16_t)t;
        } else if (EPI == 2) {
          outf[(size_t)r * ldout + col] = res[(size_t)r * 1024 + col] + b2v[col] + val;
        } else {
          outf[(size_t)r * ldout + col] += val;
        }
      }
    }
  }
}

// ---------------- fused gate: accg = xn*Wg^T (K=1024), acch = cc*Weff^T (K=128) ----------------
__global__ __launch_bounds__(256) void gate_mfma_kernel(
    const bf16_t* __restrict__ xn, const bf16_t* __restrict__ Wg,
    const bf16_t* __restrict__ cc, const bf16_t* __restrict__ Wef,
    const float* __restrict__ x, const float* __restrict__ b_g,
    float* __restrict__ xmid) {
  __shared__ __align__(16) bf16_t As[128 * 32];
  __shared__ __align__(16) bf16_t Bs[128 * 32];
  const int tid = threadIdx.x;
  const int lane = tid & 63;
  const int w = tid >> 6;
  const int wr = w >> 1, wc = w & 1;
  const int n0 = blockIdx.x * 128, r0 = blockIdx.y * 128;
  const int srow0 = tid >> 2;
  const int srow1 = 64 + (tid >> 2);
  const int skk = (tid & 3) * 8;
  const int fr = lane & 15;
  const int ko = (lane >> 4) * 8;

  f32x4 accg[4][4], acch[4][4];
  #pragma unroll
  for (int m = 0; m < 4; ++m)
    #pragma unroll
    for (int n = 0; n < 4; ++n) {
      accg[m][n] = (f32x4){0.f, 0.f, 0.f, 0.f};
      acch[m][n] = (f32x4){0.f, 0.f, 0.f, 0.f};
    }

  for (int k0 = 0; k0 < 1024; k0 += 32) {
    GLOAD16(xn + (size_t)(r0 + srow0) * 1024 + k0 + skk, (char*)As + w * 1024);
    GLOAD16(xn + (size_t)(r0 + srow1) * 1024 + k0 + skk, (char*)As + 4096 + w * 1024);
    GLOAD16(Wg + (size_t)(n0 + srow0) * 1024 + k0 + skk, (char*)Bs + w * 1024);
    GLOAD16(Wg + (size_t)(n0 + srow1) * 1024 + k0 + skk, (char*)Bs + 4096 + w * 1024);
    __syncthreads();
    bf16x8 af[4], bfr[4];
    #pragma unroll
    for (int m = 0; m < 4; ++m)
      af[m] = *(const bf16x8*)&As[(wr * 64 + m * 16 + fr) * 32 + ko];
    #pragma unroll
    for (int n = 0; n < 4; ++n)
      bfr[n] = *(const bf16x8*)&Bs[(wc * 64 + n * 16 + fr) * 32 + ko];
    #pragma unroll
    for (int m = 0; m < 4; ++m)
      #pragma unroll
      for (int n = 0; n < 4; ++n)
        accg[m][n] = __builtin_amdgcn_mfma_f32_16x16x32_bf16(af[m], bfr[n], accg[m][n], 0, 0, 0);
    __syncthreads();
  }

  for (int k0 = 0; k0 < 128; k0 += 32) {
    GLOAD16(cc + (size_t)(r0 + srow0) * 128 + k0 + skk, (char*)As + w * 1024);
    GLOAD16(cc + (size_t)(r0 + srow1) * 128 + k0 + skk, (char*)As + 4096 + w * 1024);
    GLOAD16(Wef + (size_t)(n0 + srow0) * 128 + k0 + skk, (char*)Bs + w * 1024);
    GLOAD16(Wef + (size_t)(n0 + srow1) * 128 + k0 + skk, (char*)Bs + 4096 + w * 1024);
    __syncthreads();
    bf16x8 af[4], bfr[4];
    #pragma unroll
    for (int m = 0; m < 4; ++m)
      af[m] = *(const bf16x8*)&As[(wr * 64 + m * 16 + fr) * 32 + ko];
    #pragma unroll
    for (int n = 0; n < 4; ++n)
      bfr[n] = *(const bf16x8*)&Bs[(wc * 64 + n * 16 + fr) * 32 + ko];
    #pragma unroll
    for (int m = 0; m < 4; ++m)
      #pragma unroll
      for (int n = 0; n < 4; ++n)
        acch[m][n] = __builtin_amdgcn_mfma_f32_16x16x32_bf16(af[m], bfr[n], acch[m][n], 0, 0, 0);
    __syncthreads();
  }

  const int rbase = (lane >> 4) * 4;
  #pragma unroll
  for (int m = 0; m < 4; ++m) {
    #pragma unroll
    for (int n = 0; n < 4; ++n) {
      int row = r0 + wr * 64 + m * 16 + rbase;
      int col = n0 + wc * 64 + n * 16 + fr;
      #pragma unroll
      for (int j = 0; j < 4; ++j) {
        int r = row + j;
        size_t idx = (size_t)r * 1024 + col;
        xmid[idx] = x[idx] + sigmoidf_(accg[m][n][j] + b_g[col]) * acch[m][n][j];
      }
    }
  }
}

// ---------------- elementwise: bd[16384,256] -> a,b arrays in [B,K,T] layout ----------------
__global__ __launch_bounds__(256) void ew_ab_kernel(
    const float* __restrict__ bd, const float* __restrict__ b_sel,
    const float* __restrict__ log_decay, const float* __restrict__ frequency,
    float* __restrict__ a_r, float* __restrict__ a_i,
    float* __restrict__ b_r, float* __restrict__ b_i) {
  __shared__ float T[32][257];
  int bb = blockIdx.x >> 7;            // 0..3
  int t0 = (blockIdx.x & 127) << 5;    // chunk of 32 timesteps
  int tid = threadIdx.x;
  #pragma unroll
  for (int p = 0; p < 32; ++p) {
    int idx = tid + p * 256;           // 32*256 elements
    int tt = idx >> 8, j = idx & 255;
    T[tt][j] = bd[((size_t)bb * 4096 + t0 + tt) * 256 + j];
  }
  __syncthreads();
  #pragma unroll
  for (int p = 0; p < 8; ++p) {
    int idx = tid + p * 256;           // 32 t x 64 k
    int tt = idx & 31, k = idx >> 5;
    float br_ = T[tt][k];
    float bi_ = T[tt][64 + k];
    float dd = T[tt][128 + k] + b_sel[k];
    float df = T[tt][192 + k] + b_sel[64 + k];
    float mag = sigmoidf_(log_decay[k] + 0.1f * tanhf(dd));
    float fr = frequency[k] + 0.05f * tanhf(df);
    float ar_ = mag * cosf(fr), ai_ = mag * sinf(fr);
    size_t o = ((size_t)bb * 64 + k) * 4096 + t0 + tt;
    a_r[o] = ar_; a_i[o] = ai_; b_r[o] = br_; b_i[o] = bi_;
  }
}

// ---------------- associative scan over T per (b,k); c may alias b (in-place) ----------------
__global__ __launch_bounds__(256) void scan_kernel(
    const float* __restrict__ a_r, const float* __restrict__ a_i,
    const float* b_r, const float* b_i,
    float* c_r, float* c_i) {
  int seq = blockIdx.x;                // b*64 + k
  size_t base = (size_t)seq * SEQLEN;
  int tid = threadIdx.x;
  int t0 = tid * 16;
  float Ar = 1.f, Ai = 0.f, Br = 0.f, Bi = 0.f;
  #pragma unroll
  for (int s = 0; s < 16; ++s) {
    size_t t = base + t0 + s;
    float ar = a_r[t], ai = a_i[t], br = b_r[t], bi = b_i[t];
    float nBr = ar * Br - ai * Bi + br;
    float nBi = ar * Bi + ai * Br + bi;
    Br = nBr; Bi = nBi;
    float nAr = ar * Ar - ai * Ai;
    float nAi = ar * Ai + ai * Ar;
    Ar = nAr; Ai = nAi;
  }
  __shared__ float sAr[256], sAi[256], sBr[256], sBi[256];
  sAr[tid] = Ar; sAi[tid] = Ai; sBr[tid] = Br; sBi[tid] = Bi;
  for (int off = 1; off < 256; off <<= 1) {
    __syncthreads();
    float pAr = 0.f, pAi = 0.f, pBr = 0.f, pBi = 0.f;
    if (tid >= off) { pAr = sAr[tid - off]; pAi = sAi[tid - off]; pBr = sBr[tid - off]; pBi = sBi[tid - off]; }
    __syncthreads();
    if (tid >= off) {
      float cAr = sAr[tid], cAi = sAi[tid], cBr = sBr[tid], cBi = sBi[tid];
      float nBr = cAr * pBr - cAi * pBi + cBr;
      float nBi = cAr * pBi + cAi * pBr + cBi;
      float nAr = cAr * pAr - cAi * pAi;
      float nAi = cAr * pAi + cAi * pAr;
      sAr[tid] = nAr; sAi[tid] = nAi; sBr[tid] = nBr; sBi[tid] = nBi;
    }
  }
  __syncthreads();
  float cr = (tid > 0) ? sBr[tid - 1] : 0.f;
  float ci = (tid > 0) ? sBi[tid - 1] : 0.f;
  #pragma unroll
  for (int s = 0; s < 16; ++s) {
    size_t t = base + t0 + s;
    float ar = a_r[t], ai = a_i[t], br = b_r[t], bi = b_i[t];
    float nr = ar * cr - ai * ci + br;
    float ni = ar * ci + ai * cr + bi;
    cr = nr; ci = ni;
    c_r[t] = cr; c_i[t] = ci;
  }
}

// ---------------- transpose c[B,K,T] -> cc[B*T, 128] bf16 (cols 0..63 = real, 64..127 = imag) ----------------
__global__ __launch_bounds__(256) void transpose_cc_kernel(
    const float* __restrict__ c_r, const float* __restrict__ c_i,
    bf16_t* __restrict__ cc) {
  __shared__ float Tr[64][65];
  __shared__ float Ti[64][65];
  int t0 = blockIdx.x * 64;
  int bb = blockIdx.y;
  int tid = threadIdx.x;
  int tt = tid & 63;
  int q = tid >> 6;
  #pragma unroll
  for (int p = 0; p < 16; ++p) {
    int k = p * 4 + q;
    size_t src = ((size_t)bb * 64 + k) * 4096 + t0 + tt;
    Tr[tt][k] = c_r[src];
    Ti[tt][k] = c_i[src];
  }
  __syncthreads();
  #pragma unroll
  for (int p = 0; p < 16; ++p) {
    int tt2 = p * 4 + q;
    int k = tid & 63;
    size_t row = (size_t)bb * 4096 + t0 + tt2;
    cc[row * 128 + k] = (bf16_t)Tr[tt2][k];
    cc[row * 128 + 64 + k] = (bf16_t)Ti[tt2][k];
  }
}

// ---------------- fold R into W_out: Weff[d][col] (bf16 out) ----------------
__global__ __launch_bounds__(256) void weff_kernel(const float* __restrict__ W_out,
                                                   const float* __restrict__ R,
                                                   bf16_t* __restrict__ Weff) {
  int idx = blockIdx.x * 256 + threadIdx.x;   // < 1024*128
  int d = idx >> 7, col = idx & 127;
  int k = col & 63, h = k >> 4, kk = k & 15;
  int off = (col < 64) ? 0 : 64;
  float s = 0.f;
  #pragma unroll
  for (int j = 0; j < 16; ++j)
    s += W_out[d * 128 + off + h * 16 + j] * R[h * 256 + j * 16 + kk];
  Weff[idx] = (bf16_t)s;
}

extern "C" void kernel_launch(void* const* d_in, const int* in_sizes, int n_in,
                              void* d_out, int out_size, void* d_ws, size_t ws_size,
                              hipStream_t stream) {
  (void)in_sizes; (void)n_in; (void)out_size; (void)ws_size;
  const float* x         = (const float*)d_in[0];
  const float* W_in      = (const float*)d_in[1];
  const float* log_decay = (const float*)d_in[2];
  const float* frequency = (const float*)d_in[3];
  const float* W_sel     = (const float*)d_in[4];
  const float* b_sel     = (const float*)d_in[5];
  const float* R         = (const float*)d_in[6];
  const float* W_out     = (const float*)d_in[7];
  const float* W_g       = (const float*)d_in[8];
  const float* b_g       = (const float*)d_in[9];
  const float* g1        = (const float*)d_in[10];
  const float* be1       = (const float*)d_in[11];
  const float* g2        = (const float*)d_in[12];
  const float* be2       = (const float*)d_in[13];
  const float* W1        = (const float*)d_in[14];
  const float* b1        = (const float*)d_in[15];
  const float* W2        = (const float*)d_in[16];
  const float* b2        = (const float*)d_in[17];
  float* out = (float*)d_out;
  float* ws  = (float*)d_ws;

  const size_t M1 = (size_t)1 << 20;
  float* mean1 = ws;
  float* rstd1 = ws + 16384;
  float* mean2 = ws + 32768;
  float* rstd2 = ws + 49152;
  float* a_r  = ws + 65536;
  float* a_i  = a_r + M1;
  float* b_rr = a_r + 2 * M1;
  float* b_ii = a_r + 3 * M1;
  float* bd   = a_r + 4 * M1;            // 16384 x 256 f32
  float* xmid = a_r + 8 * M1;            // 16384 x 1024 f32
  bf16_t* xn  = (bf16_t*)(a_r + 24 * M1);  // 16384 x 1024 bf16 (reused for xn2)
  bf16_t* cc  = (bf16_t*)(a_r + 32 * M1);  // 16384 x 128 bf16
  bf16_t* mid = (bf16_t*)(a_r + 33 * M1);  // 16384 x 1024 bf16 chunk
  bf16_t* Wbd = (bf16_t*)(a_r + 41 * M1);  // 256 x 1024
  bf16_t* Wgb = (bf16_t*)(a_r + 41 * M1 + (128 << 10));   // 1024 x 1024
  bf16_t* W1b = (bf16_t*)(a_r + 41 * M1 + (640 << 10));   // 4096 x 1024
  bf16_t* W2b = (bf16_t*)(a_r + 41 * M1 + (640 << 10) + 2 * M1); // 1024 x 4096
  bf16_t* Wef = (bf16_t*)(a_r + 41 * M1 + (640 << 10) + 4 * M1); // 1024 x 128

  dim3 blk(256);

  // LN1 stats + bf16 normalized activations
  ln_stats_kernel<<<NROWS, blk, 0, stream>>>(x, mean1, rstd1);
  ln_to_bf16_kernel<<<8192, blk, 0, stream>>>(x, mean1, rstd1, g1, be1, xn);

  // weight conversions
  f32_to_bf16_kernel<<<128, blk, 0, stream>>>(W_in, Wbd, 128 * 1024);
  f32_to_bf16_kernel<<<128, blk, 0, stream>>>(W_sel, Wbd + 128 * 1024, 128 * 1024);
  f32_to_bf16_kernel<<<1024, blk, 0, stream>>>(W_g, Wgb, 1024 * 1024);
  f32_to_bf16_kernel<<<4096, blk, 0, stream>>>(W1, W1b, 4 * 1024 * 1024);
  f32_to_bf16_kernel<<<4096, blk, 0, stream>>>(W2, W2b, 4 * 1024 * 1024);
  weff_kernel<<<512, blk, 0, stream>>>(W_out, R, Wef);

  // beta/delta GEMM -> bd [16384,256] f32
  gemm_bf16_kernel<0><<<dim3(2, 128), blk, 0, stream>>>(
      xn, 1024, Wbd, 1024, 1024, nullptr, nullptr, nullptr, bd, nullptr, 256);

  // elementwise a,b in [B,K,T]
  ew_ab_kernel<<<512, blk, 0, stream>>>(bd, b_sel, log_decay, frequency, a_r, a_i, b_rr, b_ii);
  // scan (c in-place over b)
  scan_kernel<<<256, blk, 0, stream>>>(a_r, a_i, b_rr, b_ii, b_rr, b_ii);
  // transpose to [B*T,128] bf16
  transpose_cc_kernel<<<dim3(64, 4), blk, 0, stream>>>(b_rr, b_ii, cc);

  // fused gate + h-projection + residual -> xmid
  gate_mfma_kernel<<<dim3(8, 128), blk, 0, stream>>>(xn, Wgb, cc, Wef, x, b_g, xmid);

  // LN2 stats + bf16 normalized (reuse xn)
  ln_stats_kernel<<<NROWS, blk, 0, stream>>>(xmid, mean2, rstd2);
  ln_to_bf16_kernel<<<8192, blk, 0, stream>>>(xmid, mean2, rstd2, g2, be2, xn);

  // MLP chunked over hidden dim (4 x 1024)
  for (int c = 0; c < 4; ++c) {
    gemm_bf16_kernel<1><<<dim3(8, 128), blk, 0, stream>>>(
        xn, 1024, W1b + (size_t)c * 1024 * 1024, 1024, 1024,
        b1 + c * 1024, nullptr, nullptr, nullptr, mid, 1024);
    if (c == 0) {
      gemm_bf16_kernel<2><<<dim3(8, 128), blk, 0, stream>>>(
          mid, 1024, W2b + (size_t)c * 1024, 4096, 1024,
          nullptr, xmid, b2, out, nullptr, 1024);
    } else {
      gemm_bf16_kernel<3><<<dim3(8, 128), blk, 0, stream>>>(
          mid, 1024, W2b + (size_t)c * 1024, 4096, 1024,
          nullptr, nullptr, nullptr, out, nullptr, 1024);
    }
  }
}

// Round 3
// 644.694 us; speedup vs baseline: 7.3765x; 1.2840x over previous
//
#include <hip/hip_runtime.h>
#include <math.h>

typedef __bf16 bf16_t;
typedef __attribute__((ext_vector_type(8))) __bf16 bf16x8;
typedef __attribute__((ext_vector_type(4))) float f32x4;

#define DMODEL 1024
#define NROWS  16384   // B*T
#define SEQLEN 4096

static __device__ __forceinline__ float sigmoidf_(float v) { return 1.f / (1.f + __expf(-v)); }

#define GLOAD16(gsrc, ldst) __builtin_amdgcn_global_load_lds(                     \
    (const __attribute__((address_space(1))) void*)(gsrc),                        \
    (__attribute__((address_space(3))) void*)(ldst), 16, 0, 0)

// ---------------- fused LayerNorm: stats + apply + f32->bf16, one block per row ----------------
__global__ __launch_bounds__(256) void ln_fused_kernel(const float* __restrict__ x,
                                                       const float* __restrict__ g,
                                                       const float* __restrict__ b,
                                                       bf16_t* __restrict__ out) {
  int row = blockIdx.x;
  int tid = threadIdx.x;
  const float4* xr = (const float4*)(x + (size_t)row * DMODEL);
  float4 v = xr[tid];
  float s  = v.x + v.y + v.z + v.w;
  float s2 = v.x*v.x + v.y*v.y + v.z*v.z + v.w*v.w;
  #pragma unroll
  for (int off = 32; off > 0; off >>= 1) {
    s  += __shfl_down(s, off);
    s2 += __shfl_down(s2, off);
  }
  __shared__ float sh[4], sh2[4];
  int lane = tid & 63, wid = tid >> 6;
  if (lane == 0) { sh[wid] = s; sh2[wid] = s2; }
  __syncthreads();
  s  = sh[0] + sh[1] + sh[2] + sh[3];
  s2 = sh2[0] + sh2[1] + sh2[2] + sh2[3];
  float m = s * (1.f / DMODEL);
  float var = fmaxf(s2 * (1.f / DMODEL) - m * m, 0.f);
  float rs = rsqrtf(var + 1e-5f);
  float4 gv = *(const float4*)&g[tid * 4];
  float4 bv = *(const float4*)&b[tid * 4];
  union { bf16_t h[4]; float2 f2; } u;
  u.h[0] = (bf16_t)((v.x - m) * rs * gv.x + bv.x);
  u.h[1] = (bf16_t)((v.y - m) * rs * gv.y + bv.y);
  u.h[2] = (bf16_t)((v.z - m) * rs * gv.z + bv.z);
  u.h[3] = (bf16_t)((v.w - m) * rs * gv.w + bv.w);
  *(float2*)&out[(size_t)row * DMODEL + tid * 4] = u.f2;
}

// ---------------- plain f32 -> bf16 convert ----------------
__global__ __launch_bounds__(256) void f32_to_bf16_kernel(const float* __restrict__ in,
                                                          bf16_t* __restrict__ out, int n) {
  int idx = (blockIdx.x * 256 + threadIdx.x) * 4;
  if (idx >= n) return;
  float4 v = *(const float4*)&in[idx];
  union { bf16_t h[4]; float2 f2; } u;
  u.h[0] = (bf16_t)v.x; u.h[1] = (bf16_t)v.y; u.h[2] = (bf16_t)v.z; u.h[3] = (bf16_t)v.w;
  *(float2*)&out[idx] = u.f2;
}

// ---------------- bf16 MFMA GEMM: C[M,N] = A[M,K] * B[N,K]^T ----------------
// 128x128 tile, BK=32, 4 waves (2x2), 4x4 frags of 16x16x32 (m97 structure).
// 1-D grid with bijective XCD swizzle, n-fastest rasterization (T1).
// EPI: 0 outf = acc (f32)
//      1 outb = bf16(silu(acc + bias[col]))
//      2 outf = res[row*1024+col] + b2v[col] + acc
template<int EPI>
__global__ __launch_bounds__(256) void gemm_bf16_kernel(
    const bf16_t* __restrict__ A, int lda,
    const bf16_t* __restrict__ B, int ldb, int K, int nx,
    const float* __restrict__ bias,
    const float* __restrict__ res, const float* __restrict__ b2v,
    float* __restrict__ outf, bf16_t* __restrict__ outb, int ldout) {
  __shared__ __align__(16) bf16_t As[128 * 32];
  __shared__ __align__(16) bf16_t Bs[128 * 32];
  const int nwg = gridDim.x;
  const int bid = blockIdx.x;
  const int lid = (bid & 7) * (nwg >> 3) + (bid >> 3);
  const int n0 = (lid % nx) * 128;
  const int r0 = (lid / nx) * 128;

  const int tid = threadIdx.x;
  const int lane = tid & 63;
  const int w = tid >> 6;
  const int wr = w >> 1, wc = w & 1;

  const int srow0 = tid >> 2;             // staging row for p=0
  const int srow1 = 64 + (tid >> 2);      // p=1
  const int skk = (tid & 3) * 8;

  const int fr = lane & 15;
  const int ko = (lane >> 4) * 8;

  f32x4 acc[4][4];
  #pragma unroll
  for (int m = 0; m < 4; ++m)
    #pragma unroll
    for (int n = 0; n < 4; ++n) acc[m][n] = (f32x4){0.f, 0.f, 0.f, 0.f};

  for (int k0 = 0; k0 < K; k0 += 32) {
    GLOAD16(A + (size_t)(r0 + srow0) * lda + k0 + skk, (char*)As + w * 1024);
    GLOAD16(A + (size_t)(r0 + srow1) * lda + k0 + skk, (char*)As + 4096 + w * 1024);
    GLOAD16(B + (size_t)(n0 + srow0) * ldb + k0 + skk, (char*)Bs + w * 1024);
    GLOAD16(B + (size_t)(n0 + srow1) * ldb + k0 + skk, (char*)Bs + 4096 + w * 1024);
    __syncthreads();
    bf16x8 af[4], bfr[4];
    #pragma unroll
    for (int m = 0; m < 4; ++m)
      af[m] = *(const bf16x8*)&As[(wr * 64 + m * 16 + fr) * 32 + ko];
    #pragma unroll
    for (int n = 0; n < 4; ++n)
      bfr[n] = *(const bf16x8*)&Bs[(wc * 64 + n * 16 + fr) * 32 + ko];
    #pragma unroll
    for (int m = 0; m < 4; ++m)
      #pragma unroll
      for (int n = 0; n < 4; ++n)
        acc[m][n] = __builtin_amdgcn_mfma_f32_16x16x32_bf16(af[m], bfr[n], acc[m][n], 0, 0, 0);
    __syncthreads();
  }

  const int rbase = (lane >> 4) * 4;
  #pragma unroll
  for (int m = 0; m < 4; ++m) {
    #pragma unroll
    for (int n = 0; n < 4; ++n) {
      int row = r0 + wr * 64 + m * 16 + rbase;
      int col = n0 + wc * 64 + n * 16 + fr;
      f32x4 v = acc[m][n];
      #pragma unroll
      for (int j = 0; j < 4; ++j) {
        int r = row + j;
        float val = v[j];
        if (EPI == 0) {
          outf[(size_t)r * ldout + col] = val;
        } else if (EPI == 1) {
          float t = val + bias[col];
          t = t * sigmoidf_(t);
          outb[(size_t)r * ldout + col] = (bf16_t)t;
        } else {
          outf[(size_t)r * ldout + col] = res[(size_t)r * 1024 + col] + b2v[col] + val;
        }
      }
    }
  }
}

// ---------------- fused gate: accg = xn*Wg^T (K=1024), acch = cc*Weff^T (K=128) ----------------
__global__ __launch_bounds__(256) void gate_mfma_kernel(
    const bf16_t* __restrict__ xn, const bf16_t* __restrict__ Wg,
    const bf16_t* __restrict__ cc, const bf16_t* __restrict__ Wef,
    const float* __restrict__ x, const float* __restrict__ b_g,
    float* __restrict__ xmid) {
  __shared__ __align__(16) bf16_t As[128 * 32];
  __shared__ __align__(16) bf16_t Bs[128 * 32];
  const int nwg = gridDim.x;
  const int bid = blockIdx.x;
  const int lid = (bid & 7) * (nwg >> 3) + (bid >> 3);
  const int n0 = (lid & 7) * 128;       // nx = 8
  const int r0 = (lid >> 3) * 128;

  const int tid = threadIdx.x;
  const int lane = tid & 63;
  const int w = tid >> 6;
  const int wr = w >> 1, wc = w & 1;
  const int srow0 = tid >> 2;
  const int srow1 = 64 + (tid >> 2);
  const int skk = (tid & 3) * 8;
  const int fr = lane & 15;
  const int ko = (lane >> 4) * 8;

  f32x4 accg[4][4], acch[4][4];
  #pragma unroll
  for (int m = 0; m < 4; ++m)
    #pragma unroll
    for (int n = 0; n < 4; ++n) {
      accg[m][n] = (f32x4){0.f, 0.f, 0.f, 0.f};
      acch[m][n] = (f32x4){0.f, 0.f, 0.f, 0.f};
    }

  for (int k0 = 0; k0 < 1024; k0 += 32) {
    GLOAD16(xn + (size_t)(r0 + srow0) * 1024 + k0 + skk, (char*)As + w * 1024);
    GLOAD16(xn + (size_t)(r0 + srow1) * 1024 + k0 + skk, (char*)As + 4096 + w * 1024);
    GLOAD16(Wg + (size_t)(n0 + srow0) * 1024 + k0 + skk, (char*)Bs + w * 1024);
    GLOAD16(Wg + (size_t)(n0 + srow1) * 1024 + k0 + skk, (char*)Bs + 4096 + w * 1024);
    __syncthreads();
    bf16x8 af[4], bfr[4];
    #pragma unroll
    for (int m = 0; m < 4; ++m)
      af[m] = *(const bf16x8*)&As[(wr * 64 + m * 16 + fr) * 32 + ko];
    #pragma unroll
    for (int n = 0; n < 4; ++n)
      bfr[n] = *(const bf16x8*)&Bs[(wc * 64 + n * 16 + fr) * 32 + ko];
    #pragma unroll
    for (int m = 0; m < 4; ++m)
      #pragma unroll
      for (int n = 0; n < 4; ++n)
        accg[m][n] = __builtin_amdgcn_mfma_f32_16x16x32_bf16(af[m], bfr[n], accg[m][n], 0, 0, 0);
    __syncthreads();
  }

  for (int k0 = 0; k0 < 128; k0 += 32) {
    GLOAD16(cc + (size_t)(r0 + srow0) * 128 + k0 + skk, (char*)As + w * 1024);
    GLOAD16(cc + (size_t)(r0 + srow1) * 128 + k0 + skk, (char*)As + 4096 + w * 1024);
    GLOAD16(Wef + (size_t)(n0 + srow0) * 128 + k0 + skk, (char*)Bs + w * 1024);
    GLOAD16(Wef + (size_t)(n0 + srow1) * 128 + k0 + skk, (char*)Bs + 4096 + w * 1024);
    __syncthreads();
    bf16x8 af[4], bfr[4];
    #pragma unroll
    for (int m = 0; m < 4; ++m)
      af[m] = *(const bf16x8*)&As[(wr * 64 + m * 16 + fr) * 32 + ko];
    #pragma unroll
    for (int n = 0; n < 4; ++n)
      bfr[n] = *(const bf16x8*)&Bs[(wc * 64 + n * 16 + fr) * 32 + ko];
    #pragma unroll
    for (int m = 0; m < 4; ++m)
      #pragma unroll
      for (int n = 0; n < 4; ++n)
        acch[m][n] = __builtin_amdgcn_mfma_f32_16x16x32_bf16(af[m], bfr[n], acch[m][n], 0, 0, 0);
    __syncthreads();
  }

  const int rbase = (lane >> 4) * 4;
  #pragma unroll
  for (int m = 0; m < 4; ++m) {
    #pragma unroll
    for (int n = 0; n < 4; ++n) {
      int row = r0 + wr * 64 + m * 16 + rbase;
      int col = n0 + wc * 64 + n * 16 + fr;
      #pragma unroll
      for (int j = 0; j < 4; ++j) {
        int r = row + j;
        size_t idx = (size_t)r * 1024 + col;
        xmid[idx] = x[idx] + sigmoidf_(accg[m][n][j] + b_g[col]) * acch[m][n][j];
      }
    }
  }
}

// ---------------- elementwise: bd[16384,256] -> a,b arrays in [B,K,T] layout ----------------
__global__ __launch_bounds__(256) void ew_ab_kernel(
    const float* __restrict__ bd, const float* __restrict__ b_sel,
    const float* __restrict__ log_decay, const float* __restrict__ frequency,
    float* __restrict__ a_r, float* __restrict__ a_i,
    float* __restrict__ b_r, float* __restrict__ b_i) {
  __shared__ float T[32][257];
  int bb = blockIdx.x >> 7;            // 0..3
  int t0 = (blockIdx.x & 127) << 5;    // chunk of 32 timesteps
  int tid = threadIdx.x;
  #pragma unroll
  for (int p = 0; p < 32; ++p) {
    int idx = tid + p * 256;           // 32*256 elements
    int tt = idx >> 8, j = idx & 255;
    T[tt][j] = bd[((size_t)bb * 4096 + t0 + tt) * 256 + j];
  }
  __syncthreads();
  #pragma unroll
  for (int p = 0; p < 8; ++p) {
    int idx = tid + p * 256;           // 32 t x 64 k
    int tt = idx & 31, k = idx >> 5;
    float br_ = T[tt][k];
    float bi_ = T[tt][64 + k];
    float dd = T[tt][128 + k] + b_sel[k];
    float df = T[tt][192 + k] + b_sel[64 + k];
    float mag = sigmoidf_(log_decay[k] + 0.1f * tanhf(dd));
    float fr = frequency[k] + 0.05f * tanhf(df);
    float ar_ = mag * cosf(fr), ai_ = mag * sinf(fr);
    size_t o = ((size_t)bb * 64 + k) * 4096 + t0 + tt;
    a_r[o] = ar_; a_i[o] = ai_; b_r[o] = br_; b_i[o] = bi_;
  }
}

// ---------------- associative scan over T per (b,k); c in-place over b ----------------
__global__ __launch_bounds__(256) void scan_kernel(
    const float* __restrict__ a_r, const float* __restrict__ a_i,
    const float* b_r, const float* b_i,
    float* c_r, float* c_i) {
  int seq = blockIdx.x;                // b*64 + k
  size_t base = (size_t)seq * SEQLEN;
  int tid = threadIdx.x;
  int t0 = tid * 16;
  float Ar = 1.f, Ai = 0.f, Br = 0.f, Bi = 0.f;
  #pragma unroll
  for (int s = 0; s < 16; ++s) {
    size_t t = base + t0 + s;
    float ar = a_r[t], ai = a_i[t], br = b_r[t], bi = b_i[t];
    float nBr = ar * Br - ai * Bi + br;
    float nBi = ar * Bi + ai * Br + bi;
    Br = nBr; Bi = nBi;
    float nAr = ar * Ar - ai * Ai;
    float nAi = ar * Ai + ai * Ar;
    Ar = nAr; Ai = nAi;
  }
  __shared__ float sAr[256], sAi[256], sBr[256], sBi[256];
  sAr[tid] = Ar; sAi[tid] = Ai; sBr[tid] = Br; sBi[tid] = Bi;
  for (int off = 1; off < 256; off <<= 1) {
    __syncthreads();
    float pAr = 0.f, pAi = 0.f, pBr = 0.f, pBi = 0.f;
    if (tid >= off) { pAr = sAr[tid - off]; pAi = sAi[tid - off]; pBr = sBr[tid - off]; pBi = sBi[tid - off]; }
    __syncthreads();
    if (tid >= off) {
      float cAr = sAr[tid], cAi = sAi[tid], cBr = sBr[tid], cBi = sBi[tid];
      float nBr = cAr * pBr - cAi * pBi + cBr;
      float nBi = cAr * pBi + cAi * pBr + cBi;
      float nAr = cAr * pAr - cAi * pAi;
      float nAi = cAr * pAi + cAi * pAr;
      sAr[tid] = nAr; sAi[tid] = nAi; sBr[tid] = nBr; sBi[tid] = nBi;
    }
  }
  __syncthreads();
  float cr = (tid > 0) ? sBr[tid - 1] : 0.f;
  float ci = (tid > 0) ? sBi[tid - 1] : 0.f;
  #pragma unroll
  for (int s = 0; s < 16; ++s) {
    size_t t = base + t0 + s;
    float ar = a_r[t], ai = a_i[t], br = b_r[t], bi = b_i[t];
    float nr = ar * cr - ai * ci + br;
    float ni = ar * ci + ai * cr + bi;
    cr = nr; ci = ni;
    c_r[t] = cr; c_i[t] = ci;
  }
}

// ---------------- transpose c[B,K,T] -> cc[B*T, 128] bf16 ----------------
__global__ __launch_bounds__(256) void transpose_cc_kernel(
    const float* __restrict__ c_r, const float* __restrict__ c_i,
    bf16_t* __restrict__ cc) {
  __shared__ float Tr[64][65];
  __shared__ float Ti[64][65];
  int t0 = blockIdx.x * 64;
  int bb = blockIdx.y;
  int tid = threadIdx.x;
  int tt = tid & 63;
  int q = tid >> 6;
  #pragma unroll
  for (int p = 0; p < 16; ++p) {
    int k = p * 4 + q;
    size_t src = ((size_t)bb * 64 + k) * 4096 + t0 + tt;
    Tr[tt][k] = c_r[src];
    Ti[tt][k] = c_i[src];
  }
  __syncthreads();
  #pragma unroll
  for (int p = 0; p < 16; ++p) {
    int tt2 = p * 4 + q;
    int k = tid & 63;
    size_t row = (size_t)bb * 4096 + t0 + tt2;
    cc[row * 128 + k] = (bf16_t)Tr[tt2][k];
    cc[row * 128 + 64 + k] = (bf16_t)Ti[tt2][k];
  }
}

// ---------------- fold R into W_out: Weff[d][col] (bf16 out) ----------------
__global__ __launch_bounds__(256) void weff_kernel(const float* __restrict__ W_out,
                                                   const float* __restrict__ R,
                                                   bf16_t* __restrict__ Weff) {
  int idx = blockIdx.x * 256 + threadIdx.x;   // < 1024*128
  int d = idx >> 7, col = idx & 127;
  int k = col & 63, h = k >> 4, kk = k & 15;
  int off = (col < 64) ? 0 : 64;
  float s = 0.f;
  #pragma unroll
  for (int j = 0; j < 16; ++j)
    s += W_out[d * 128 + off + h * 16 + j] * R[h * 256 + j * 16 + kk];
  Weff[idx] = (bf16_t)s;
}

extern "C" void kernel_launch(void* const* d_in, const int* in_sizes, int n_in,
                              void* d_out, int out_size, void* d_ws, size_t ws_size,
                              hipStream_t stream) {
  (void)in_sizes; (void)n_in; (void)out_size; (void)ws_size;
  const float* x         = (const float*)d_in[0];
  const float* W_in      = (const float*)d_in[1];
  const float* log_decay = (const float*)d_in[2];
  const float* frequency = (const float*)d_in[3];
  const float* W_sel     = (const float*)d_in[4];
  const float* b_sel     = (const float*)d_in[5];
  const float* R         = (const float*)d_in[6];
  const float* W_out     = (const float*)d_in[7];
  const float* W_g       = (const float*)d_in[8];
  const float* b_g       = (const float*)d_in[9];
  const float* g1        = (const float*)d_in[10];
  const float* be1       = (const float*)d_in[11];
  const float* g2        = (const float*)d_in[12];
  const float* be2       = (const float*)d_in[13];
  const float* W1        = (const float*)d_in[14];
  const float* b1        = (const float*)d_in[15];
  const float* W2        = (const float*)d_in[16];
  const float* b2        = (const float*)d_in[17];
  float* out = (float*)d_out;
  float* ws  = (float*)d_ws;

  const size_t M1 = (size_t)1 << 20;
  // ws layout (floats):
  //  [0, 16M)    : xmid f32 (64 MB); first 4M floats double as bd (dead before xmid written)
  //  [16M, 32M)  : scan arrays a_r,a_i,b_r,b_i (4 x 4M f32); after transpose reused as mid bf16 (8192x4096)
  //  [32M, 40M)  : xn bf16 (16384x1024)
  //  [40M, 41M)  : cc bf16 (16384x128)
  //  [41M, ...)  : weights bf16
  float* bd   = ws;                    // 16384 x 256 f32
  float* xmid = ws;                    // 16384 x 1024 f32
  float* a_r  = ws + 16 * M1;
  float* a_i  = a_r + 4 * M1;
  float* b_rr = a_r + 8 * M1;
  float* b_ii = a_r + 12 * M1;
  bf16_t* mid = (bf16_t*)(ws + 16 * M1);   // 8192 x 4096 bf16 per chunk
  bf16_t* xn  = (bf16_t*)(ws + 32 * M1);   // 16384 x 1024 bf16
  bf16_t* cc  = (bf16_t*)(ws + 40 * M1);   // 16384 x 128 bf16
  bf16_t* Wbd = (bf16_t*)(ws + 41 * M1);                  // 256 x 1024
  bf16_t* Wgb = (bf16_t*)(ws + 41 * M1 + (128 << 10));    // 1024 x 1024
  bf16_t* W1b = (bf16_t*)(ws + 41 * M1 + (640 << 10));    // 4096 x 1024
  bf16_t* W2b = (bf16_t*)(ws + 43 * M1 + (640 << 10));    // 1024 x 4096
  bf16_t* Wef = (bf16_t*)(ws + 45 * M1 + (640 << 10));    // 1024 x 128

  dim3 blk(256);

  // LN1 fused -> xn bf16
  ln_fused_kernel<<<NROWS, blk, 0, stream>>>(x, g1, be1, xn);

  // weight conversions
  f32_to_bf16_kernel<<<128, blk, 0, stream>>>(W_in, Wbd, 128 * 1024);
  f32_to_bf16_kernel<<<128, blk, 0, stream>>>(W_sel, Wbd + 128 * 1024, 128 * 1024);
  f32_to_bf16_kernel<<<1024, blk, 0, stream>>>(W_g, Wgb, 1024 * 1024);
  f32_to_bf16_kernel<<<4096, blk, 0, stream>>>(W1, W1b, 4 * 1024 * 1024);
  f32_to_bf16_kernel<<<4096, blk, 0, stream>>>(W2, W2b, 4 * 1024 * 1024);
  weff_kernel<<<512, blk, 0, stream>>>(W_out, R, Wef);

  // beta/delta GEMM -> bd [16384,256] f32   (grid 2 x 128 = 256, nx=2)
  gemm_bf16_kernel<0><<<256, blk, 0, stream>>>(
      xn, 1024, Wbd, 1024, 1024, 2, nullptr, nullptr, nullptr, bd, nullptr, 256);

  // elementwise a,b in [B,K,T]
  ew_ab_kernel<<<512, blk, 0, stream>>>(bd, b_sel, log_decay, frequency, a_r, a_i, b_rr, b_ii);
  // scan (c in-place over b)
  scan_kernel<<<256, blk, 0, stream>>>(a_r, a_i, b_rr, b_ii, b_rr, b_ii);
  // transpose to [B*T,128] bf16
  transpose_cc_kernel<<<dim3(64, 4), blk, 0, stream>>>(b_rr, b_ii, cc);

  // fused gate + h-projection + residual -> xmid   (grid 8 x 128 = 1024, nx=8)
  gate_mfma_kernel<<<1024, blk, 0, stream>>>(xn, Wgb, cc, Wef, x, b_g, xmid);

  // LN2 fused -> xn bf16 (reuse)
  ln_fused_kernel<<<NROWS, blk, 0, stream>>>(xmid, g2, be2, xn);

  // MLP chunked over M (2 chunks of 8192 rows), full K each
  for (int c = 0; c < 2; ++c) {
    size_t ro = (size_t)c * 8192;
    // W1: [8192,1024] x [4096,1024]^T -> mid bf16 (silu)   grid 32 x 64 = 2048, nx=32
    gemm_bf16_kernel<1><<<2048, blk, 0, stream>>>(
        xn + ro * 1024, 1024, W1b, 1024, 1024, 32,
        b1, nullptr, nullptr, nullptr, mid, 4096);
    // W2: [8192,4096] x [1024,4096]^T -> out (res + b2)    grid 8 x 64 = 512, nx=8
    gemm_bf16_kernel<2><<<512, blk, 0, stream>>>(
        mid, 4096, W2b, 4096, 4096, 8,
        nullptr, xmid + ro * 1024, b2, out + ro * 1024, nullptr, 1024);
  }
}

// Round 4
// 544.991 us; speedup vs baseline: 8.7260x; 1.1829x over previous
//
#include <hip/hip_runtime.h>
#include <math.h>

typedef __bf16 bf16_t;
typedef __attribute__((ext_vector_type(8))) __bf16 bf16x8;
typedef __attribute__((ext_vector_type(4))) float f32x4;

#define DMODEL 1024
#define NROWS  16384   // B*T
#define SEQLEN 4096

static __device__ __forceinline__ float sigmoidf_(float v) { return 1.f / (1.f + __expf(-v)); }

#define GLOAD16(gsrc, ldst) __builtin_amdgcn_global_load_lds(                     \
    (const __attribute__((address_space(1))) void*)(gsrc),                        \
    (__attribute__((address_space(3))) void*)(ldst), 16, 0, 0)

// ---------------- fused LayerNorm: stats + apply + f32->bf16, one block per row ----------------
__global__ __launch_bounds__(256) void ln_fused_kernel(const float* __restrict__ x,
                                                       const float* __restrict__ g,
                                                       const float* __restrict__ b,
                                                       bf16_t* __restrict__ out) {
  int row = blockIdx.x;
  int tid = threadIdx.x;
  const float4* xr = (const float4*)(x + (size_t)row * DMODEL);
  float4 v = xr[tid];
  float s  = v.x + v.y + v.z + v.w;
  float s2 = v.x*v.x + v.y*v.y + v.z*v.z + v.w*v.w;
  #pragma unroll
  for (int off = 32; off > 0; off >>= 1) {
    s  += __shfl_down(s, off);
    s2 += __shfl_down(s2, off);
  }
  __shared__ float sh[4], sh2[4];
  int lane = tid & 63, wid = tid >> 6;
  if (lane == 0) { sh[wid] = s; sh2[wid] = s2; }
  __syncthreads();
  s  = sh[0] + sh[1] + sh[2] + sh[3];
  s2 = sh2[0] + sh2[1] + sh2[2] + sh2[3];
  float m = s * (1.f / DMODEL);
  float var = fmaxf(s2 * (1.f / DMODEL) - m * m, 0.f);
  float rs = rsqrtf(var + 1e-5f);
  float4 gv = *(const float4*)&g[tid * 4];
  float4 bv = *(const float4*)&b[tid * 4];
  union { bf16_t h[4]; float2 f2; } u;
  u.h[0] = (bf16_t)((v.x - m) * rs * gv.x + bv.x);
  u.h[1] = (bf16_t)((v.y - m) * rs * gv.y + bv.y);
  u.h[2] = (bf16_t)((v.z - m) * rs * gv.z + bv.z);
  u.h[3] = (bf16_t)((v.w - m) * rs * gv.w + bv.w);
  *(float2*)&out[(size_t)row * DMODEL + tid * 4] = u.f2;
}

// ---------------- plain f32 -> bf16 convert ----------------
__global__ __launch_bounds__(256) void f32_to_bf16_kernel(const float* __restrict__ in,
                                                          bf16_t* __restrict__ out, int n) {
  int idx = (blockIdx.x * 256 + threadIdx.x) * 4;
  if (idx >= n) return;
  float4 v = *(const float4*)&in[idx];
  union { bf16_t h[4]; float2 f2; } u;
  u.h[0] = (bf16_t)v.x; u.h[1] = (bf16_t)v.y; u.h[2] = (bf16_t)v.z; u.h[3] = (bf16_t)v.w;
  *(float2*)&out[idx] = u.f2;
}

// ================= 256x256 / BK=64 / 8-wave bf16 MFMA engine =================
// C[M,N] = A[M,K] * B[N,K]^T, 512 threads (2x4 waves), per-wave 128x64 output.
// LDS: double-buffered K-tiles, st_16x32 XOR swizzle (bit9 -> bit5).
// One __syncthreads per K-tile; next tile staged (global_load_lds w=16, source
// pre-swizzled) before the 64-MFMA compute block.
// EPI: 0 outf = acc
//      1 outb = bf16(silu(acc + bias[col]))
//      2 outf = res[r*1024+col] + bias[col] + acc
//      3 outf += acc
//      4 outf = res[idx] + sigmoid(acc + bias[col]) * aux[idx]   (idx = r*1024+col)
template<int EPI>
__global__ __launch_bounds__(512, 2) void gemm256_kernel(
    const bf16_t* __restrict__ A, int lda,
    const bf16_t* __restrict__ B, int ldb, int K, int nx,
    const float* __restrict__ bias,
    const float* __restrict__ res,
    const float* __restrict__ aux,
    float* __restrict__ outf, bf16_t* __restrict__ outb, int ldout) {
  __shared__ __align__(1024) char lds[2][2][32768];   // [dbuf][A/B][256 rows x 64 bf16]
  const int nwg = gridDim.x;
  const int bid = blockIdx.x;
  const int lid = (bid & 7) * (nwg >> 3) + (bid >> 3);   // bijective XCD swizzle (nwg%8==0)
  const int n0 = (lid % nx) * 256;
  const int r0 = (lid / nx) * 256;

  const int tid = threadIdx.x;
  const int lane = tid & 63;
  const int w = tid >> 6;              // wave 0..7
  const int wr = w >> 2, wc = w & 3;   // 2 x 4 wave grid
  const int fr = lane & 15;
  // swizzled k-byte base for fragment reads: (q*16) ^ (((row>>2)&1)<<5), row bit2 == lane bit2
  const int q16m = ((lane >> 4) * 16) ^ (((lane >> 2) & 1) << 5);
  // staging: linear LDS dest (i*8192 + w*1024 + lane*16); source row/col from swizzled offset
  const int srow = w * 8 + (lane >> 3);                  // + i*64
  const int scolb = ((lane & 7) * 16) ^ (lane & 32);     // byte col, bit5 flipped for lanes>=32

  f32x4 acc[8][4];
  #pragma unroll
  for (int m = 0; m < 8; ++m)
    #pragma unroll
    for (int n = 0; n < 4; ++n) acc[m][n] = (f32x4){0.f, 0.f, 0.f, 0.f};

  const int nt = K >> 6;

  auto stage = [&](int d, int k0) {
    #pragma unroll
    for (int i = 0; i < 4; ++i) {
      GLOAD16((const char*)(A + (size_t)(r0 + i * 64 + srow) * lda + k0) + scolb,
              lds[d][0] + i * 8192 + w * 1024);
      GLOAD16((const char*)(B + (size_t)(n0 + i * 64 + srow) * ldb + k0) + scolb,
              lds[d][1] + i * 8192 + w * 1024);
    }
  };

  auto compute = [&](int d) {
    bf16x8 bfrag[4][2];
    #pragma unroll
    for (int n = 0; n < 4; ++n) {
      const char* bp = lds[d][1] + (wc * 64 + n * 16 + fr) * 128 + q16m;
      bfrag[n][0] = *(const bf16x8*)bp;
      bfrag[n][1] = *(const bf16x8*)(bp + 64);
    }
    #pragma unroll
    for (int mh = 0; mh < 2; ++mh) {
      bf16x8 afrag[4][2];
      #pragma unroll
      for (int m = 0; m < 4; ++m) {
        const char* ap = lds[d][0] + (wr * 128 + mh * 64 + m * 16 + fr) * 128 + q16m;
        afrag[m][0] = *(const bf16x8*)ap;
        afrag[m][1] = *(const bf16x8*)(ap + 64);
      }
      #pragma unroll
      for (int m = 0; m < 4; ++m)
        #pragma unroll
        for (int n = 0; n < 4; ++n) {
          acc[mh * 4 + m][n] = __builtin_amdgcn_mfma_f32_16x16x32_bf16(afrag[m][0], bfrag[n][0], acc[mh * 4 + m][n], 0, 0, 0);
          acc[mh * 4 + m][n] = __builtin_amdgcn_mfma_f32_16x16x32_bf16(afrag[m][1], bfrag[n][1], acc[mh * 4 + m][n], 0, 0, 0);
        }
    }
  };

  stage(0, 0);
  __syncthreads();
  for (int t = 0; t < nt; ++t) {
    if (t + 1 < nt) stage((t + 1) & 1, (t + 1) << 6);
    compute(t & 1);
    __syncthreads();
  }

  const int rbase = (lane >> 4) * 4;
  #pragma unroll
  for (int mf = 0; mf < 8; ++mf) {
    #pragma unroll
    for (int n = 0; n < 4; ++n) {
      int row = r0 + wr * 128 + mf * 16 + rbase;
      int col = n0 + wc * 64 + n * 16 + fr;
      f32x4 v = acc[mf][n];
      #pragma unroll
      for (int j = 0; j < 4; ++j) {
        int r = row + j;
        float val = v[j];
        if (EPI == 0) {
          outf[(size_t)r * ldout + col] = val;
        } else if (EPI == 1) {
          float t2 = val + bias[col];
          t2 = t2 * sigmoidf_(t2);
          outb[(size_t)r * ldout + col] = (bf16_t)t2;
        } else if (EPI == 2) {
          outf[(size_t)r * ldout + col] = res[(size_t)r * 1024 + col] + bias[col] + val;
        } else if (EPI == 3) {
          outf[(size_t)r * ldout + col] += val;
        } else {
          size_t idx = (size_t)r * 1024 + col;
          outf[idx] = res[idx] + sigmoidf_(val + bias[col]) * aux[idx];
        }
      }
    }
  }
}

// ---------------- legacy 128x128 engine (beta/delta GEMM only) ----------------
template<int EPI>
__global__ __launch_bounds__(256) void gemm_bf16_kernel(
    const bf16_t* __restrict__ A, int lda,
    const bf16_t* __restrict__ B, int ldb, int K, int nx,
    float* __restrict__ outf, int ldout) {
  __shared__ __align__(16) bf16_t As[128 * 32];
  __shared__ __align__(16) bf16_t Bs[128 * 32];
  const int nwg = gridDim.x;
  const int bid = blockIdx.x;
  const int lid = (bid & 7) * (nwg >> 3) + (bid >> 3);
  const int n0 = (lid % nx) * 128;
  const int r0 = (lid / nx) * 128;

  const int tid = threadIdx.x;
  const int lane = tid & 63;
  const int w = tid >> 6;
  const int wr = w >> 1, wc = w & 1;
  const int srow0 = tid >> 2;
  const int srow1 = 64 + (tid >> 2);
  const int skk = (tid & 3) * 8;
  const int fr = lane & 15;
  const int ko = (lane >> 4) * 8;

  f32x4 acc[4][4];
  #pragma unroll
  for (int m = 0; m < 4; ++m)
    #pragma unroll
    for (int n = 0; n < 4; ++n) acc[m][n] = (f32x4){0.f, 0.f, 0.f, 0.f};

  for (int k0 = 0; k0 < K; k0 += 32) {
    GLOAD16(A + (size_t)(r0 + srow0) * lda + k0 + skk, (char*)As + w * 1024);
    GLOAD16(A + (size_t)(r0 + srow1) * lda + k0 + skk, (char*)As + 4096 + w * 1024);
    GLOAD16(B + (size_t)(n0 + srow0) * ldb + k0 + skk, (char*)Bs + w * 1024);
    GLOAD16(B + (size_t)(n0 + srow1) * ldb + k0 + skk, (char*)Bs + 4096 + w * 1024);
    __syncthreads();
    bf16x8 af[4], bfr[4];
    #pragma unroll
    for (int m = 0; m < 4; ++m)
      af[m] = *(const bf16x8*)&As[(wr * 64 + m * 16 + fr) * 32 + ko];
    #pragma unroll
    for (int n = 0; n < 4; ++n)
      bfr[n] = *(const bf16x8*)&Bs[(wc * 64 + n * 16 + fr) * 32 + ko];
    #pragma unroll
    for (int m = 0; m < 4; ++m)
      #pragma unroll
      for (int n = 0; n < 4; ++n)
        acc[m][n] = __builtin_amdgcn_mfma_f32_16x16x32_bf16(af[m], bfr[n], acc[m][n], 0, 0, 0);
    __syncthreads();
  }

  const int rbase = (lane >> 4) * 4;
  #pragma unroll
  for (int m = 0; m < 4; ++m) {
    #pragma unroll
    for (int n = 0; n < 4; ++n) {
      int row = r0 + wr * 64 + m * 16 + rbase;
      int col = n0 + wc * 64 + n * 16 + fr;
      f32x4 v = acc[m][n];
      #pragma unroll
      for (int j = 0; j < 4; ++j)
        outf[(size_t)(row + j) * ldout + col] = v[j];
    }
  }
}

// ---------------- elementwise: bd[16384,256] -> a,b arrays in [B,K,T] layout ----------------
__global__ __launch_bounds__(256) void ew_ab_kernel(
    const float* __restrict__ bd, const float* __restrict__ b_sel,
    const float* __restrict__ log_decay, const float* __restrict__ frequency,
    float* __restrict__ a_r, float* __restrict__ a_i,
    float* __restrict__ b_r, float* __restrict__ b_i) {
  __shared__ float T[32][257];
  int bb = blockIdx.x >> 7;            // 0..3
  int t0 = (blockIdx.x & 127) << 5;    // chunk of 32 timesteps
  int tid = threadIdx.x;
  #pragma unroll
  for (int p = 0; p < 32; ++p) {
    int idx = tid + p * 256;
    int tt = idx >> 8, j = idx & 255;
    T[tt][j] = bd[((size_t)bb * 4096 + t0 + tt) * 256 + j];
  }
  __syncthreads();
  #pragma unroll
  for (int p = 0; p < 8; ++p) {
    int idx = tid + p * 256;
    int tt = idx & 31, k = idx >> 5;
    float br_ = T[tt][k];
    float bi_ = T[tt][64 + k];
    float dd = T[tt][128 + k] + b_sel[k];
    float df = T[tt][192 + k] + b_sel[64 + k];
    float mag = sigmoidf_(log_decay[k] + 0.1f * tanhf(dd));
    float fr = frequency[k] + 0.05f * tanhf(df);
    float ar_ = mag * cosf(fr), ai_ = mag * sinf(fr);
    size_t o = ((size_t)bb * 64 + k) * 4096 + t0 + tt;
    a_r[o] = ar_; a_i[o] = ai_; b_r[o] = br_; b_i[o] = bi_;
  }
}

// ---------------- associative scan over T per (b,k); c in-place over b ----------------
__global__ __launch_bounds__(256) void scan_kernel(
    const float* __restrict__ a_r, const float* __restrict__ a_i,
    const float* b_r, const float* b_i,
    float* c_r, float* c_i) {
  int seq = blockIdx.x;
  size_t base = (size_t)seq * SEQLEN;
  int tid = threadIdx.x;
  int t0 = tid * 16;
  float Ar = 1.f, Ai = 0.f, Br = 0.f, Bi = 0.f;
  #pragma unroll
  for (int s = 0; s < 16; ++s) {
    size_t t = base + t0 + s;
    float ar = a_r[t], ai = a_i[t], br = b_r[t], bi = b_i[t];
    float nBr = ar * Br - ai * Bi + br;
    float nBi = ar * Bi + ai * Br + bi;
    Br = nBr; Bi = nBi;
    float nAr = ar * Ar - ai * Ai;
    float nAi = ar * Ai + ai * Ar;
    Ar = nAr; Ai = nAi;
  }
  __shared__ float sAr[256], sAi[256], sBr[256], sBi[256];
  sAr[tid] = Ar; sAi[tid] = Ai; sBr[tid] = Br; sBi[tid] = Bi;
  for (int off = 1; off < 256; off <<= 1) {
    __syncthreads();
    float pAr = 0.f, pAi = 0.f, pBr = 0.f, pBi = 0.f;
    if (tid >= off) { pAr = sAr[tid - off]; pAi = sAi[tid - off]; pBr = sBr[tid - off]; pBi = sBi[tid - off]; }
    __syncthreads();
    if (tid >= off) {
      float cAr = sAr[tid], cAi = sAi[tid], cBr = sBr[tid], cBi = sBi[tid];
      float nBr = cAr * pBr - cAi * pBi + cBr;
      float nBi = cAr * pBi + cAi * pBr + cBi;
      float nAr = cAr * pAr - cAi * pAi;
      float nAi = cAr * pAi + cAi * pAr;
      sAr[tid] = nAr; sAi[tid] = nAi; sBr[tid] = nBr; sBi[tid] = nBi;
    }
  }
  __syncthreads();
  float cr = (tid > 0) ? sBr[tid - 1] : 0.f;
  float ci = (tid > 0) ? sBi[tid - 1] : 0.f;
  #pragma unroll
  for (int s = 0; s < 16; ++s) {
    size_t t = base + t0 + s;
    float ar = a_r[t], ai = a_i[t], br = b_r[t], bi = b_i[t];
    float nr = ar * cr - ai * ci + br;
    float ni = ar * ci + ai * cr + bi;
    cr = nr; ci = ni;
    c_r[t] = cr; c_i[t] = ci;
  }
}

// ---------------- transpose c[B,K,T] -> cc[B*T, 128] bf16 ----------------
__global__ __launch_bounds__(256) void transpose_cc_kernel(
    const float* __restrict__ c_r, const float* __restrict__ c_i,
    bf16_t* __restrict__ cc) {
  __shared__ float Tr[64][65];
  __shared__ float Ti[64][65];
  int t0 = blockIdx.x * 64;
  int bb = blockIdx.y;
  int tid = threadIdx.x;
  int tt = tid & 63;
  int q = tid >> 6;
  #pragma unroll
  for (int p = 0; p < 16; ++p) {
    int k = p * 4 + q;
    size_t src = ((size_t)bb * 64 + k) * 4096 + t0 + tt;
    Tr[tt][k] = c_r[src];
    Ti[tt][k] = c_i[src];
  }
  __syncthreads();
  #pragma unroll
  for (int p = 0; p < 16; ++p) {
    int tt2 = p * 4 + q;
    int k = tid & 63;
    size_t row = (size_t)bb * 4096 + t0 + tt2;
    cc[row * 128 + k] = (bf16_t)Tr[tt2][k];
    cc[row * 128 + 64 + k] = (bf16_t)Ti[tt2][k];
  }
}

// ---------------- fold R into W_out: Weff[d][col] (bf16 out) ----------------
__global__ __launch_bounds__(256) void weff_kernel(const float* __restrict__ W_out,
                                                   const float* __restrict__ R,
                                                   bf16_t* __restrict__ Weff) {
  int idx = blockIdx.x * 256 + threadIdx.x;   // < 1024*128
  int d = idx >> 7, col = idx & 127;
  int k = col & 63, h = k >> 4, kk = k & 15;
  int off = (col < 64) ? 0 : 64;
  float s = 0.f;
  #pragma unroll
  for (int j = 0; j < 16; ++j)
    s += W_out[d * 128 + off + h * 16 + j] * R[h * 256 + j * 16 + kk];
  Weff[idx] = (bf16_t)s;
}

extern "C" void kernel_launch(void* const* d_in, const int* in_sizes, int n_in,
                              void* d_out, int out_size, void* d_ws, size_t ws_size,
                              hipStream_t stream) {
  (void)in_sizes; (void)n_in; (void)out_size; (void)ws_size;
  const float* x         = (const float*)d_in[0];
  const float* W_in      = (const float*)d_in[1];
  const float* log_decay = (const float*)d_in[2];
  const float* frequency = (const float*)d_in[3];
  const float* W_sel     = (const float*)d_in[4];
  const float* b_sel     = (const float*)d_in[5];
  const float* R         = (const float*)d_in[6];
  const float* W_out     = (const float*)d_in[7];
  const float* W_g       = (const float*)d_in[8];
  const float* b_g       = (const float*)d_in[9];
  const float* g1        = (const float*)d_in[10];
  const float* be1       = (const float*)d_in[11];
  const float* g2        = (const float*)d_in[12];
  const float* be2       = (const float*)d_in[13];
  const float* W1        = (const float*)d_in[14];
  const float* b1        = (const float*)d_in[15];
  const float* W2        = (const float*)d_in[16];
  const float* b2        = (const float*)d_in[17];
  float* out = (float*)d_out;
  float* ws  = (float*)d_ws;

  const size_t M1 = (size_t)1 << 20;
  // ws layout (f32 units). Live ranges:
  //  [0,16M)   : bd (GEMM1->ew, dead) then xmid f32 (gate -> last W2)
  //  [16M,32M) : a_r/a_i/b_rr/b_ii (ew->transpose) -> hbuf f32 (hgemm->gate) -> mid bf16 (W1->W2, 16384x2048)
  //  [32M,40M) : xn bf16 (LN1 out; reused for LN2 out)
  //  [40M,41M) : cc bf16
  //  [41M,...) : weights bf16  (total ~183 MB, proven footprint)
  float* bd   = ws;
  float* xmid = ws;
  float* a_r  = ws + 16 * M1;
  float* a_i  = ws + 20 * M1;
  float* b_rr = ws + 24 * M1;
  float* b_ii = ws + 28 * M1;
  float* hbuf = ws + 16 * M1;
  bf16_t* mid = (bf16_t*)(ws + 16 * M1);   // 16384 x 2048 bf16
  bf16_t* xn  = (bf16_t*)(ws + 32 * M1);
  bf16_t* cc  = (bf16_t*)(ws + 40 * M1);
  bf16_t* Wbd = (bf16_t*)(ws + 41 * M1);                  // 256 x 1024
  bf16_t* Wgb = (bf16_t*)(ws + 41 * M1 + (128 << 10));    // 1024 x 1024
  bf16_t* W1b = (bf16_t*)(ws + 41 * M1 + (640 << 10));    // 4096 x 1024
  bf16_t* W2b = (bf16_t*)(ws + 43 * M1 + (640 << 10));    // 1024 x 4096
  bf16_t* Wef = (bf16_t*)(ws + 45 * M1 + (640 << 10));    // 1024 x 128

  dim3 blk(256);
  dim3 blk512(512);

  // LN1 fused -> xn bf16
  ln_fused_kernel<<<NROWS, blk, 0, stream>>>(x, g1, be1, xn);

  // weight conversions
  f32_to_bf16_kernel<<<128, blk, 0, stream>>>(W_in, Wbd, 128 * 1024);
  f32_to_bf16_kernel<<<128, blk, 0, stream>>>(W_sel, Wbd + 128 * 1024, 128 * 1024);
  f32_to_bf16_kernel<<<1024, blk, 0, stream>>>(W_g, Wgb, 1024 * 1024);
  f32_to_bf16_kernel<<<4096, blk, 0, stream>>>(W1, W1b, 4 * 1024 * 1024);
  f32_to_bf16_kernel<<<4096, blk, 0, stream>>>(W2, W2b, 4 * 1024 * 1024);
  weff_kernel<<<512, blk, 0, stream>>>(W_out, R, Wef);

  // beta/delta GEMM -> bd [16384,256] f32  (legacy engine; grid 256, nx=2)
  gemm_bf16_kernel<0><<<256, blk, 0, stream>>>(xn, 1024, Wbd, 1024, 1024, 2, bd, 256);

  // elementwise a,b in [B,K,T]
  ew_ab_kernel<<<512, blk, 0, stream>>>(bd, b_sel, log_decay, frequency, a_r, a_i, b_rr, b_ii);
  // scan (c in-place over b)
  scan_kernel<<<256, blk, 0, stream>>>(a_r, a_i, b_rr, b_ii, b_rr, b_ii);
  // transpose to [B*T,128] bf16
  transpose_cc_kernel<<<dim3(64, 4), blk, 0, stream>>>(b_rr, b_ii, cc);

  // h-projection: hbuf = cc @ Weff^T   (M=16384,N=1024,K=128; grid 256)
  gemm256_kernel<0><<<256, blk512, 0, stream>>>(
      cc, 128, Wef, 128, 128, 4, nullptr, nullptr, nullptr, hbuf, nullptr, 1024);

  // gate GEMM + fuse: xmid = x + sigmoid(xn@Wg^T + b_g) * hbuf   (grid 256)
  gemm256_kernel<4><<<256, blk512, 0, stream>>>(
      xn, 1024, Wgb, 1024, 1024, 4, b_g, x, hbuf, xmid, nullptr, 1024);

  // LN2 fused -> xn bf16 (reuse)
  ln_fused_kernel<<<NROWS, blk, 0, stream>>>(xmid, g2, be2, xn);

  // MLP: chunk over hidden dim (2 x 2048), full-M GEMMs, 2-pass W2 accumulation
  for (int h = 0; h < 2; ++h) {
    // W1 slice: mid = silu(xn @ W1[h]^T + b1[h])  (M=16384,N=2048,K=1024; grid 512)
    gemm256_kernel<1><<<512, blk512, 0, stream>>>(
        xn, 1024, W1b + (size_t)h * 2048 * 1024, 1024, 1024, 8,
        b1 + h * 2048, nullptr, nullptr, nullptr, mid, 2048);
    // W2 partial: out (+)= mid @ W2[:,h]^T  (M=16384,N=1024,K=2048; grid 256)
    if (h == 0) {
      gemm256_kernel<2><<<256, blk512, 0, stream>>>(
          mid, 2048, W2b, 4096, 2048, 4,
          b2, xmid, nullptr, out, nullptr, 1024);
    } else {
      gemm256_kernel<3><<<256, blk512, 0, stream>>>(
          mid, 2048, W2b + 2048, 4096, 2048, 4,
          nullptr, nullptr, nullptr, out, nullptr, 1024);
    }
  }
}

// Round 5
// 526.954 us; speedup vs baseline: 9.0247x; 1.0342x over previous
//
#include <hip/hip_runtime.h>
#include <math.h>

typedef __bf16 bf16_t;
typedef __attribute__((ext_vector_type(8))) __bf16 bf16x8;
typedef __attribute__((ext_vector_type(4))) float f32x4;

#define DMODEL 1024
#define NROWS  16384   // B*T
#define SEQLEN 4096

static __device__ __forceinline__ float sigmoidf_(float v) { return 1.f / (1.f + __expf(-v)); }

#define GLOAD16(gsrc, ldst) __builtin_amdgcn_global_load_lds(                     \
    (const __attribute__((address_space(1))) void*)(gsrc),                        \
    (__attribute__((address_space(3))) void*)(ldst), 16, 0, 0)

// ---------------- fused LayerNorm: stats + apply + f32->bf16, one block per row ----------------
__global__ __launch_bounds__(256) void ln_fused_kernel(const float* __restrict__ x,
                                                       const float* __restrict__ g,
                                                       const float* __restrict__ b,
                                                       bf16_t* __restrict__ out) {
  int row = blockIdx.x;
  int tid = threadIdx.x;
  const float4* xr = (const float4*)(x + (size_t)row * DMODEL);
  float4 v = xr[tid];
  float s  = v.x + v.y + v.z + v.w;
  float s2 = v.x*v.x + v.y*v.y + v.z*v.z + v.w*v.w;
  #pragma unroll
  for (int off = 32; off > 0; off >>= 1) {
    s  += __shfl_down(s, off);
    s2 += __shfl_down(s2, off);
  }
  __shared__ float sh[4], sh2[4];
  int lane = tid & 63, wid = tid >> 6;
  if (lane == 0) { sh[wid] = s; sh2[wid] = s2; }
  __syncthreads();
  s  = sh[0] + sh[1] + sh[2] + sh[3];
  s2 = sh2[0] + sh2[1] + sh2[2] + sh2[3];
  float m = s * (1.f / DMODEL);
  float var = fmaxf(s2 * (1.f / DMODEL) - m * m, 0.f);
  float rs = rsqrtf(var + 1e-5f);
  float4 gv = *(const float4*)&g[tid * 4];
  float4 bv = *(const float4*)&b[tid * 4];
  union { bf16_t h[4]; float2 f2; } u;
  u.h[0] = (bf16_t)((v.x - m) * rs * gv.x + bv.x);
  u.h[1] = (bf16_t)((v.y - m) * rs * gv.y + bv.y);
  u.h[2] = (bf16_t)((v.z - m) * rs * gv.z + bv.z);
  u.h[3] = (bf16_t)((v.w - m) * rs * gv.w + bv.w);
  *(float2*)&out[(size_t)row * DMODEL + tid * 4] = u.f2;
}

// ---------------- plain f32 -> bf16 convert ----------------
__global__ __launch_bounds__(256) void f32_to_bf16_kernel(const float* __restrict__ in,
                                                          bf16_t* __restrict__ out, int n) {
  int idx = (blockIdx.x * 256 + threadIdx.x) * 4;
  if (idx >= n) return;
  float4 v = *(const float4*)&in[idx];
  union { bf16_t h[4]; float2 f2; } u;
  u.h[0] = (bf16_t)v.x; u.h[1] = (bf16_t)v.y; u.h[2] = (bf16_t)v.z; u.h[3] = (bf16_t)v.w;
  *(float2*)&out[idx] = u.f2;
}

// ================= 256x256 / BK=64 / 8-wave / 8-phase bf16 MFMA engine =================
// C[M,N] = A[M,K]*B[N,K]^T. 512 thr (2M x 4N waves), wave tile 128x64.
// LDS 128KB: A/B K-tile double buffers, halves: A by 64-row quadrant (mh), B by 32-col quadrant (nn).
// 3-bit XOR swizzle col ^= (row&7)<<4 applied on gload source AND ds_read (involution).
// 4 phases per K-tile: (mh0,nn0)(mh0,nn1)(mh1,nn0)(mh1,nn1); 16 MFMA each, setprio-wrapped.
// Staging leads consumption by 7 half-tiles; vmcnt(6) once per K-tile boundary; epilogue tile no-prefetch.
#define LOADA(d, mh)                                                              \
  { _Pragma("unroll")                                                             \
    for (int m_ = 0; m_ < 4; ++m_) {                                              \
      _Pragma("unroll")                                                           \
      for (int kk_ = 0; kk_ < 2; ++kk_)                                           \
        afrag[m_][kk_] = *(const bf16x8*)(ldsp + (d) * 32768 + (mh) * 16384 +     \
            (aRow + m_ * 16) * 128 + ((kk_ * 64 + q16) ^ swz));                   \
    } }

#define LOADB(d, nn)                                                              \
  { _Pragma("unroll")                                                             \
    for (int n2_ = 0; n2_ < 2; ++n2_) {                                           \
      _Pragma("unroll")                                                           \
      for (int kk_ = 0; kk_ < 2; ++kk_)                                           \
        bfrag[nn][n2_][kk_] = *(const bf16x8*)(ldsp + 65536 + (d) * 32768 +       \
            (nn) * 16384 + (bRow + n2_ * 16) * 128 + ((kk_ * 64 + q16) ^ swz));   \
    } }

#define MFMAQ(mh, nn)                                                             \
  { _Pragma("unroll")                                                             \
    for (int m_ = 0; m_ < 4; ++m_) {                                              \
      _Pragma("unroll")                                                           \
      for (int n2_ = 0; n2_ < 2; ++n2_) {                                         \
        acc[(mh)*4+m_][(nn)*2+n2_] = __builtin_amdgcn_mfma_f32_16x16x32_bf16(     \
            afrag[m_][0], bfrag[nn][n2_][0], acc[(mh)*4+m_][(nn)*2+n2_], 0,0,0);  \
        acc[(mh)*4+m_][(nn)*2+n2_] = __builtin_amdgcn_mfma_f32_16x16x32_bf16(     \
            afrag[m_][1], bfrag[nn][n2_][1], acc[(mh)*4+m_][(nn)*2+n2_], 0,0,0);  \
      }                                                                           \
    } }

#define PH_PRE()  __builtin_amdgcn_s_barrier();                                   \
                  asm volatile("s_waitcnt lgkmcnt(0)");                           \
                  __builtin_amdgcn_sched_barrier(0);                              \
                  __builtin_amdgcn_s_setprio(1)
#define PH_POST() __builtin_amdgcn_s_setprio(0);                                  \
                  __builtin_amdgcn_s_barrier()

// EPI: 0 outf=acc; 1 outb=bf16(silu(acc+bias)); 2 outf=res+bias+acc; 3 outf+=acc;
//      4 outf = res[idx] + sigmoid(acc+bias[col]) * aux[idx]
template<int EPI>
__global__ __launch_bounds__(512, 2) void gemm256_kernel(
    const bf16_t* __restrict__ A, int lda,
    const bf16_t* __restrict__ B, int ldb, int K, int nx,
    const float* __restrict__ bias,
    const float* __restrict__ res,
    const float* __restrict__ aux,
    float* __restrict__ outf, bf16_t* __restrict__ outb, int ldout) {
  __shared__ __align__(128) char ldsp[131072];
  const int nwg = gridDim.x;
  const int bid = blockIdx.x;
  const int lid = (bid & 7) * (nwg >> 3) + (bid >> 3);   // bijective XCD swizzle (nwg%8==0)
  const int n0 = (lid % nx) * 256;
  const int r0 = (lid / nx) * 256;

  const int tid = threadIdx.x;
  const int lane = tid & 63;
  const int w = tid >> 6;
  const int wr = w >> 2, wc = w & 3;
  const int fr = lane & 15;
  const int q16 = (lane >> 4) * 16;
  const int swz = (fr & 7) << 4;
  const int aRow = wr * 64 + fr;
  const int bRow = wc * 32 + fr;

  const size_t lda_b = (size_t)lda * 2;
  const size_t ldb_b = (size_t)ldb * 2;
  const char* Ab = (const char*)A;
  const char* Bb = (const char*)B;
  const int trow = tid >> 3;
  const int scolb = (((tid & 7) ^ (trow & 7)) << 4);

  // A-half h of buf d: LDS rows rho = j*64 + trow <-> global row r0 + j*128 + h*64 + trow
  auto stageA = [&](int d, int h, int kt) {
    const char* src = Ab + (size_t)(r0 + h * 64 + trow) * lda_b + kt * 128 + scolb;
    char* dst = ldsp + d * 32768 + h * 16384 + tid * 16;
    GLOAD16(src, dst);
    GLOAD16(src + 128 * lda_b, dst + 8192);
  };
  // B-half g of buf d: rho = j*64+trow <-> global row n0 + (rho>>5)*64 + g*32 + (rho&31)
  auto stageB = [&](int d, int g, int kt) {
    const int r1 = 64 + trow;
    const char* s0 = Bb + (size_t)(n0 + (trow >> 5) * 64 + g * 32 + (trow & 31)) * ldb_b + kt * 128 + scolb;
    const char* s1 = Bb + (size_t)(n0 + (r1 >> 5) * 64 + g * 32 + (r1 & 31)) * ldb_b + kt * 128 + scolb;
    char* dst = ldsp + 65536 + d * 32768 + g * 16384 + tid * 16;
    GLOAD16(s0, dst);
    GLOAD16(s1, dst + 8192);
  };

  f32x4 acc[8][4];
  #pragma unroll
  for (int m = 0; m < 8; ++m)
    #pragma unroll
    for (int n = 0; n < 4; ++n) acc[m][n] = (f32x4){0.f, 0.f, 0.f, 0.f};
  bf16x8 afrag[4][2];
  bf16x8 bfrag[2][2][2];

  const int nt = K >> 6;

  // prologue: stage tile0 (first-use order) + 3 halves of tile1
  stageA(0, 0, 0); stageB(0, 0, 0); stageB(0, 1, 0); stageA(0, 1, 0);
  if (nt > 1) {
    stageA(1, 0, 1); stageB(1, 0, 1); stageB(1, 1, 1);
    asm volatile("s_waitcnt vmcnt(6)");
  } else {
    asm volatile("s_waitcnt vmcnt(0)");
  }
  __builtin_amdgcn_s_barrier();

  for (int t = 0; t < nt - 1; ++t) {
    const int d = t & 1, dn = d ^ 1;
    // ph0: quadrant (mh0,nn0); stage A1(t+1)
    LOADA(d, 0) LOADB(d, 0)
    stageA(dn, 1, t + 1);
    PH_PRE(); MFMAQ(0, 0) PH_POST();
    // ph1: quadrant (mh0,nn1); stage A0(t+2)
    LOADB(d, 1)
    if (t + 2 < nt) stageA(d, 0, t + 2);
    PH_PRE(); MFMAQ(0, 1) PH_POST();
    // ph2: quadrant (mh1,nn0); stage B0(t+2)
    LOADA(d, 1)
    if (t + 2 < nt) stageB(d, 0, t + 2);
    PH_PRE(); MFMAQ(1, 0) PH_POST();
    // ph3: quadrant (mh1,nn1); stage B1(t+2); K-tile boundary vmcnt
    if (t + 2 < nt) stageB(d, 1, t + 2);
    __builtin_amdgcn_s_barrier();
    __builtin_amdgcn_s_setprio(1);
    MFMAQ(1, 1)
    __builtin_amdgcn_s_setprio(0);
    if (t == nt - 2) { asm volatile("s_waitcnt vmcnt(0)"); }
    else             { asm volatile("s_waitcnt vmcnt(6)"); }
    __builtin_amdgcn_s_barrier();
  }
  // epilogue K-tile: no prefetch
  {
    const int d = (nt - 1) & 1;
    LOADA(d, 0) LOADB(d, 0)
    asm volatile("s_waitcnt lgkmcnt(0)");
    __builtin_amdgcn_sched_barrier(0);
    MFMAQ(0, 0)
    LOADB(d, 1)
    asm volatile("s_waitcnt lgkmcnt(0)");
    __builtin_amdgcn_sched_barrier(0);
    MFMAQ(0, 1)
    LOADA(d, 1)
    asm volatile("s_waitcnt lgkmcnt(0)");
    __builtin_amdgcn_sched_barrier(0);
    MFMAQ(1, 0)
    MFMAQ(1, 1)
  }

  const int rbase = (lane >> 4) * 4;
  #pragma unroll
  for (int mf = 0; mf < 8; ++mf) {
    #pragma unroll
    for (int n = 0; n < 4; ++n) {
      int row = r0 + wr * 128 + mf * 16 + rbase;
      int col = n0 + wc * 64 + n * 16 + fr;
      f32x4 v = acc[mf][n];
      #pragma unroll
      for (int j = 0; j < 4; ++j) {
        int r = row + j;
        float val = v[j];
        if (EPI == 0) {
          outf[(size_t)r * ldout + col] = val;
        } else if (EPI == 1) {
          float t2 = val + bias[col];
          t2 = t2 * sigmoidf_(t2);
          outb[(size_t)r * ldout + col] = (bf16_t)t2;
        } else if (EPI == 2) {
          outf[(size_t)r * ldout + col] = res[(size_t)r * 1024 + col] + bias[col] + val;
        } else if (EPI == 3) {
          outf[(size_t)r * ldout + col] += val;
        } else {
          size_t idx = (size_t)r * 1024 + col;
          outf[idx] = res[idx] + sigmoidf_(val + bias[col]) * aux[idx];
        }
      }
    }
  }
}

// ---------------- legacy 128x128 engine (beta/delta GEMM only) ----------------
template<int EPI>
__global__ __launch_bounds__(256) void gemm_bf16_kernel(
    const bf16_t* __restrict__ A, int lda,
    const bf16_t* __restrict__ B, int ldb, int K, int nx,
    float* __restrict__ outf, int ldout) {
  __shared__ __align__(16) bf16_t As[128 * 32];
  __shared__ __align__(16) bf16_t Bs[128 * 32];
  const int nwg = gridDim.x;
  const int bid = blockIdx.x;
  const int lid = (bid & 7) * (nwg >> 3) + (bid >> 3);
  const int n0 = (lid % nx) * 128;
  const int r0 = (lid / nx) * 128;

  const int tid = threadIdx.x;
  const int lane = tid & 63;
  const int w = tid >> 6;
  const int wr = w >> 1, wc = w & 1;
  const int srow0 = tid >> 2;
  const int srow1 = 64 + (tid >> 2);
  const int skk = (tid & 3) * 8;
  const int fr = lane & 15;
  const int ko = (lane >> 4) * 8;

  f32x4 acc[4][4];
  #pragma unroll
  for (int m = 0; m < 4; ++m)
    #pragma unroll
    for (int n = 0; n < 4; ++n) acc[m][n] = (f32x4){0.f, 0.f, 0.f, 0.f};

  for (int k0 = 0; k0 < K; k0 += 32) {
    GLOAD16(A + (size_t)(r0 + srow0) * lda + k0 + skk, (char*)As + w * 1024);
    GLOAD16(A + (size_t)(r0 + srow1) * lda + k0 + skk, (char*)As + 4096 + w * 1024);
    GLOAD16(B + (size_t)(n0 + srow0) * ldb + k0 + skk, (char*)Bs + w * 1024);
    GLOAD16(B + (size_t)(n0 + srow1) * ldb + k0 + skk, (char*)Bs + 4096 + w * 1024);
    __syncthreads();
    bf16x8 af[4], bfr[4];
    #pragma unroll
    for (int m = 0; m < 4; ++m)
      af[m] = *(const bf16x8*)&As[(wr * 64 + m * 16 + fr) * 32 + ko];
    #pragma unroll
    for (int n = 0; n < 4; ++n)
      bfr[n] = *(const bf16x8*)&Bs[(wc * 64 + n * 16 + fr) * 32 + ko];
    #pragma unroll
    for (int m = 0; m < 4; ++m)
      #pragma unroll
      for (int n = 0; n < 4; ++n)
        acc[m][n] = __builtin_amdgcn_mfma_f32_16x16x32_bf16(af[m], bfr[n], acc[m][n], 0, 0, 0);
    __syncthreads();
  }

  const int rbase = (lane >> 4) * 4;
  #pragma unroll
  for (int m = 0; m < 4; ++m) {
    #pragma unroll
    for (int n = 0; n < 4; ++n) {
      int row = r0 + wr * 64 + m * 16 + rbase;
      int col = n0 + wc * 64 + n * 16 + fr;
      f32x4 v = acc[m][n];
      #pragma unroll
      for (int j = 0; j < 4; ++j)
        outf[(size_t)(row + j) * ldout + col] = v[j];
    }
  }
}

// ---------------- elementwise: bd[16384,256] -> a,b arrays in [B,K,T] layout ----------------
__global__ __launch_bounds__(256) void ew_ab_kernel(
    const float* __restrict__ bd, const float* __restrict__ b_sel,
    const float* __restrict__ log_decay, const float* __restrict__ frequency,
    float* __restrict__ a_r, float* __restrict__ a_i,
    float* __restrict__ b_r, float* __restrict__ b_i) {
  __shared__ float T[32][257];
  int bb = blockIdx.x >> 7;            // 0..3
  int t0 = (blockIdx.x & 127) << 5;    // chunk of 32 timesteps
  int tid = threadIdx.x;
  #pragma unroll
  for (int p = 0; p < 32; ++p) {
    int idx = tid + p * 256;
    int tt = idx >> 8, j = idx & 255;
    T[tt][j] = bd[((size_t)bb * 4096 + t0 + tt) * 256 + j];
  }
  __syncthreads();
  #pragma unroll
  for (int p = 0; p < 8; ++p) {
    int idx = tid + p * 256;
    int tt = idx & 31, k = idx >> 5;
    float br_ = T[tt][k];
    float bi_ = T[tt][64 + k];
    float dd = T[tt][128 + k] + b_sel[k];
    float df = T[tt][192 + k] + b_sel[64 + k];
    float mag = sigmoidf_(log_decay[k] + 0.1f * tanhf(dd));
    float fr = frequency[k] + 0.05f * tanhf(df);
    float ar_ = mag * cosf(fr), ai_ = mag * sinf(fr);
    size_t o = ((size_t)bb * 64 + k) * 4096 + t0 + tt;
    a_r[o] = ar_; a_i[o] = ai_; b_r[o] = br_; b_i[o] = bi_;
  }
}

// ---------------- associative scan over T per (b,k); c in-place over b ----------------
__global__ __launch_bounds__(256) void scan_kernel(
    const float* __restrict__ a_r, const float* __restrict__ a_i,
    const float* b_r, const float* b_i,
    float* c_r, float* c_i) {
  int seq = blockIdx.x;
  size_t base = (size_t)seq * SEQLEN;
  int tid = threadIdx.x;
  int t0 = tid * 16;
  float Ar = 1.f, Ai = 0.f, Br = 0.f, Bi = 0.f;
  #pragma unroll
  for (int s = 0; s < 16; ++s) {
    size_t t = base + t0 + s;
    float ar = a_r[t], ai = a_i[t], br = b_r[t], bi = b_i[t];
    float nBr = ar * Br - ai * Bi + br;
    float nBi = ar * Bi + ai * Br + bi;
    Br = nBr; Bi = nBi;
    float nAr = ar * Ar - ai * Ai;
    float nAi = ar * Ai + ai * Ar;
    Ar = nAr; Ai = nAi;
  }
  __shared__ float sAr[256], sAi[256], sBr[256], sBi[256];
  sAr[tid] = Ar; sAi[tid] = Ai; sBr[tid] = Br; sBi[tid] = Bi;
  for (int off = 1; off < 256; off <<= 1) {
    __syncthreads();
    float pAr = 0.f, pAi = 0.f, pBr = 0.f, pBi = 0.f;
    if (tid >= off) { pAr = sAr[tid - off]; pAi = sAi[tid - off]; pBr = sBr[tid - off]; pBi = sBi[tid - off]; }
    __syncthreads();
    if (tid >= off) {
      float cAr = sAr[tid], cAi = sAi[tid], cBr = sBr[tid], cBi = sBi[tid];
      float nBr = cAr * pBr - cAi * pBi + cBr;
      float nBi = cAr * pBi + cAi * pBr + cBi;
      float nAr = cAr * pAr - cAi * pAi;
      float nAi = cAr * pAi + cAi * pAr;
      sAr[tid] = nAr; sAi[tid] = nAi; sBr[tid] = nBr; sBi[tid] = nBi;
    }
  }
  __syncthreads();
  float cr = (tid > 0) ? sBr[tid - 1] : 0.f;
  float ci = (tid > 0) ? sBi[tid - 1] : 0.f;
  #pragma unroll
  for (int s = 0; s < 16; ++s) {
    size_t t = base + t0 + s;
    float ar = a_r[t], ai = a_i[t], br = b_r[t], bi = b_i[t];
    float nr = ar * cr - ai * ci + br;
    float ni = ar * ci + ai * cr + bi;
    cr = nr; ci = ni;
    c_r[t] = cr; c_i[t] = ci;
  }
}

// ---------------- transpose c[B,K,T] -> cc[B*T, 128] bf16 ----------------
__global__ __launch_bounds__(256) void transpose_cc_kernel(
    const float* __restrict__ c_r, const float* __restrict__ c_i,
    bf16_t* __restrict__ cc) {
  __shared__ float Tr[64][65];
  __shared__ float Ti[64][65];
  int t0 = blockIdx.x * 64;
  int bb = blockIdx.y;
  int tid = threadIdx.x;
  int tt = tid & 63;
  int q = tid >> 6;
  #pragma unroll
  for (int p = 0; p < 16; ++p) {
    int k = p * 4 + q;
    size_t src = ((size_t)bb * 64 + k) * 4096 + t0 + tt;
    Tr[tt][k] = c_r[src];
    Ti[tt][k] = c_i[src];
  }
  __syncthreads();
  #pragma unroll
  for (int p = 0; p < 16; ++p) {
    int tt2 = p * 4 + q;
    int k = tid & 63;
    size_t row = (size_t)bb * 4096 + t0 + tt2;
    cc[row * 128 + k] = (bf16_t)Tr[tt2][k];
    cc[row * 128 + 64 + k] = (bf16_t)Ti[tt2][k];
  }
}

// ---------------- fold R into W_out: Weff[d][col] (bf16 out) ----------------
__global__ __launch_bounds__(256) void weff_kernel(const float* __restrict__ W_out,
                                                   const float* __restrict__ R,
                                                   bf16_t* __restrict__ Weff) {
  int idx = blockIdx.x * 256 + threadIdx.x;   // < 1024*128
  int d = idx >> 7, col = idx & 127;
  int k = col & 63, h = k >> 4, kk = k & 15;
  int off = (col < 64) ? 0 : 64;
  float s = 0.f;
  #pragma unroll
  for (int j = 0; j < 16; ++j)
    s += W_out[d * 128 + off + h * 16 + j] * R[h * 256 + j * 16 + kk];
  Weff[idx] = (bf16_t)s;
}

extern "C" void kernel_launch(void* const* d_in, const int* in_sizes, int n_in,
                              void* d_out, int out_size, void* d_ws, size_t ws_size,
                              hipStream_t stream) {
  (void)in_sizes; (void)n_in; (void)out_size; (void)ws_size;
  const float* x         = (const float*)d_in[0];
  const float* W_in      = (const float*)d_in[1];
  const float* log_decay = (const float*)d_in[2];
  const float* frequency = (const float*)d_in[3];
  const float* W_sel     = (const float*)d_in[4];
  const float* b_sel     = (const float*)d_in[5];
  const float* R         = (const float*)d_in[6];
  const float* W_out     = (const float*)d_in[7];
  const float* W_g       = (const float*)d_in[8];
  const float* b_g       = (const float*)d_in[9];
  const float* g1        = (const float*)d_in[10];
  const float* be1       = (const float*)d_in[11];
  const float* g2        = (const float*)d_in[12];
  const float* be2       = (const float*)d_in[13];
  const float* W1        = (const float*)d_in[14];
  const float* b1        = (const float*)d_in[15];
  const float* W2        = (const float*)d_in[16];
  const float* b2        = (const float*)d_in[17];
  float* out = (float*)d_out;
  float* ws  = (float*)d_ws;

  const size_t M1 = (size_t)1 << 20;
  float* bd   = ws;                        // 16384 x 256 f32 (dead before xmid)
  float* xmid = ws;                        // 16384 x 1024 f32
  float* a_r  = ws + 16 * M1;
  float* a_i  = ws + 20 * M1;
  float* b_rr = ws + 24 * M1;
  float* b_ii = ws + 28 * M1;
  float* hbuf = ws + 16 * M1;
  bf16_t* mid = (bf16_t*)(ws + 16 * M1);   // 16384 x 2048 bf16 per half
  bf16_t* xn  = (bf16_t*)(ws + 32 * M1);
  bf16_t* cc  = (bf16_t*)(ws + 40 * M1);
  bf16_t* Wbd = (bf16_t*)(ws + 41 * M1);                  // 256 x 1024
  bf16_t* Wgb = (bf16_t*)(ws + 41 * M1 + (128 << 10));    // 1024 x 1024
  bf16_t* W1b = (bf16_t*)(ws + 41 * M1 + (640 << 10));    // 4096 x 1024
  bf16_t* W2b = (bf16_t*)(ws + 43 * M1 + (640 << 10));    // 1024 x 4096
  bf16_t* Wef = (bf16_t*)(ws + 45 * M1 + (640 << 10));    // 1024 x 128

  dim3 blk(256);
  dim3 blk512(512);

  // LN1 fused -> xn bf16
  ln_fused_kernel<<<NROWS, blk, 0, stream>>>(x, g1, be1, xn);

  // weight conversions
  f32_to_bf16_kernel<<<128, blk, 0, stream>>>(W_in, Wbd, 128 * 1024);
  f32_to_bf16_kernel<<<128, blk, 0, stream>>>(W_sel, Wbd + 128 * 1024, 128 * 1024);
  f32_to_bf16_kernel<<<1024, blk, 0, stream>>>(W_g, Wgb, 1024 * 1024);
  f32_to_bf16_kernel<<<4096, blk, 0, stream>>>(W1, W1b, 4 * 1024 * 1024);
  f32_to_bf16_kernel<<<4096, blk, 0, stream>>>(W2, W2b, 4 * 1024 * 1024);
  weff_kernel<<<512, blk, 0, stream>>>(W_out, R, Wef);

  // beta/delta GEMM -> bd [16384,256] f32  (legacy engine; grid 256, nx=2)
  gemm_bf16_kernel<0><<<256, blk, 0, stream>>>(xn, 1024, Wbd, 1024, 1024, 2, bd, 256);

  // elementwise a,b in [B,K,T]
  ew_ab_kernel<<<512, blk, 0, stream>>>(bd, b_sel, log_decay, frequency, a_r, a_i, b_rr, b_ii);
  // scan (c in-place over b)
  scan_kernel<<<256, blk, 0, stream>>>(a_r, a_i, b_rr, b_ii, b_rr, b_ii);
  // transpose to [B*T,128] bf16
  transpose_cc_kernel<<<dim3(64, 4), blk, 0, stream>>>(b_rr, b_ii, cc);

  // h-projection: hbuf = cc @ Weff^T   (M=16384,N=1024,K=128; grid 256, nx=4)
  gemm256_kernel<0><<<256, blk512, 0, stream>>>(
      cc, 128, Wef, 128, 128, 4, nullptr, nullptr, nullptr, hbuf, nullptr, 1024);

  // gate GEMM + fuse: xmid = x + sigmoid(xn@Wg^T + b_g) * hbuf   (grid 256, nx=4)
  gemm256_kernel<4><<<256, blk512, 0, stream>>>(
      xn, 1024, Wgb, 1024, 1024, 4, b_g, x, hbuf, xmid, nullptr, 1024);

  // LN2 fused -> xn bf16 (reuse)
  ln_fused_kernel<<<NROWS, blk, 0, stream>>>(xmid, g2, be2, xn);

  // MLP: chunk over hidden dim (2 x 2048), full-M GEMMs, 2-pass W2 accumulation
  for (int h = 0; h < 2; ++h) {
    // W1 slice: mid = silu(xn @ W1[h]^T + b1[h])  (M=16384,N=2048,K=1024; grid 512, nx=8)
    gemm256_kernel<1><<<512, blk512, 0, stream>>>(
        xn, 1024, W1b + (size_t)h * 2048 * 1024, 1024, 1024, 8,
        b1 + h * 2048, nullptr, nullptr, nullptr, mid, 2048);
    // W2 partial: out (+)= mid @ W2[:,h]^T  (M=16384,N=1024,K=2048; grid 256, nx=4)
    if (h == 0) {
      gemm256_kernel<2><<<256, blk512, 0, stream>>>(
          mid, 2048, W2b, 4096, 2048, 4,
          b2, xmid, nullptr, out, nullptr, 1024);
    } else {
      gemm256_kernel<3><<<256, blk512, 0, stream>>>(
          mid, 2048, W2b + 2048, 4096, 2048, 4,
          nullptr, nullptr, nullptr, out, nullptr, 1024);
    }
  }
}